// Round 1
// baseline (2855.652 us; speedup 1.0000x reference)
//
#include <hip/hip_runtime.h>
#include <hip/hip_bf16.h>
#include <math.h>

// Dynamic_MHGCN_FusionLayer: B=256, N=131, IN=512, OUT=1024, H=4, D=256
// Round 1: correctness-first fp32 pipeline. Node GEMMs are classic 64x64x16
// LDS-tiled SGEMM with float4 LDS fragment reads. Attention normalization and
// node_att scaling are folded into the aggregation GEMM coefficients.

#define LRELU(x) ((x) > 0.f ? (x) : 0.01f * (x))

constexpr int Bb = 256;
constexpr int Nn = 131;
constexpr int INF_ = 512;
constexpr int OUTF = 1024;
constexpr int Hh = 4;
constexpr int Dd = 256;

// ---------------------------------------------------------------------------
// Generic tiled GEMM: C[m,o] = lrelu( sum_k A[m,k] * W[o,k] + bias[o] )
// A: [M,K] row-major, W: [O,K] row-major. BM=BO=64, BK=16, 256 threads,
// each thread computes a 4x4 sub-tile (4 consecutive rows x 4 consecutive cols).
// Requires M%64==0, K%16==0, O%64==0 (true for all call sites).
// ---------------------------------------------------------------------------
__global__ __launch_bounds__(256) void gemm_aw(
    const float* __restrict__ A, const float* __restrict__ W,
    const float* __restrict__ bias, float* __restrict__ C,
    int M, int K, int O)
{
    __shared__ float As[16][68];  // [k][m], pad 68 -> write conflicts <=2-way (free)
    __shared__ float Ws[16][68];  // [k][o]
    const int tid = threadIdx.x;
    const int tx = tid & 15;       // o group
    const int ty = tid >> 4;       // m group
    const int m0 = blockIdx.y * 64;
    const int o0 = blockIdx.x * 64;

    float acc[4][4] = {};

    for (int k0 = 0; k0 < K; k0 += 16) {
        const int j = tid & 15;    // k offset
        const int i = tid >> 4;    // row offset base (0..15), rows i+16r
        #pragma unroll
        for (int r = 0; r < 4; ++r)
            As[j][i + 16 * r] = A[(size_t)(m0 + i + 16 * r) * K + k0 + j];
        #pragma unroll
        for (int r = 0; r < 4; ++r)
            Ws[j][i + 16 * r] = W[(size_t)(o0 + i + 16 * r) * K + k0 + j];
        __syncthreads();
        #pragma unroll
        for (int kk = 0; kk < 16; ++kk) {
            const float4 av = *(const float4*)&As[kk][ty * 4];
            const float4 wv = *(const float4*)&Ws[kk][tx * 4];
            const float a[4] = {av.x, av.y, av.z, av.w};
            const float w[4] = {wv.x, wv.y, wv.z, wv.w};
            #pragma unroll
            for (int r = 0; r < 4; ++r)
                #pragma unroll
                for (int c = 0; c < 4; ++c)
                    acc[r][c] += a[r] * w[c];
        }
        __syncthreads();
    }

    #pragma unroll
    for (int r = 0; r < 4; ++r) {
        const int m = m0 + ty * 4 + r;
        const int o = o0 + tx * 4;
        float4 v;
        float* vp = (float*)&v;
        #pragma unroll
        for (int c = 0; c < 4; ++c) {
            float t = acc[r][c] + (bias ? bias[o + c] : 0.f);
            vp[c] = LRELU(t);
        }
        *(float4*)&C[(size_t)m * O + o] = v;
    }
}

// ---------------------------------------------------------------------------
// node_att: scores s[b,n] = (1/32) * sum_o T_q[b,o] * G_k[b,n,o]
// softmax over n (131), +1, write [B,N] to d_out att region.
// One block (4 waves) per batch.
// ---------------------------------------------------------------------------
__global__ __launch_bounds__(256) void nodeatt_kernel(
    const float* __restrict__ Tq, const float* __restrict__ Gk,
    float* __restrict__ att)
{
    const int b = blockIdx.x;
    __shared__ float tq[OUTF];
    __shared__ float sc[136];
    const int tid = threadIdx.x;
    for (int o = tid; o < OUTF; o += 256) tq[o] = Tq[(size_t)b * OUTF + o];
    __syncthreads();

    const int wave = tid >> 6, lane = tid & 63;
    for (int n = wave; n < Nn; n += 4) {
        const float* gk = Gk + ((size_t)b * Nn + n) * OUTF;
        float s = 0.f;
        for (int o = lane; o < OUTF; o += 64) s += tq[o] * gk[o];
        #pragma unroll
        for (int off = 32; off; off >>= 1) s += __shfl_xor(s, off);
        if (lane == 0) sc[n] = s * (1.f / 32.f);
    }
    __syncthreads();

    if (tid < 64) {
        const float v1 = sc[lane];
        const float v2 = sc[lane + 64];
        const float v3 = (lane < 3) ? sc[lane + 128] : -1e30f;
        float m = fmaxf(fmaxf(v1, v2), v3);
        #pragma unroll
        for (int off = 32; off; off >>= 1) m = fmaxf(m, __shfl_xor(m, off));
        const float e1 = expf(v1 - m);
        const float e2 = expf(v2 - m);
        const float e3 = (lane < 3) ? expf(v3 - m) : 0.f;
        float s = e1 + e2 + e3;
        #pragma unroll
        for (int off = 32; off; off >>= 1) s += __shfl_xor(s, off);
        const float inv = 1.f / s;
        float* ab = att + (size_t)b * Nn;
        ab[lane] = e1 * inv + 1.f;
        ab[lane + 64] = e2 * inv + 1.f;
        if (lane < 3) ab[lane + 128] = e3 * inv + 1.f;
    }
}

// ---------------------------------------------------------------------------
// edge_att[b,h,x,y] = sigmoid( (1/16) * sum_d Gq[b,x,h*256+d] * Gk[b,y,h*256+d] )
// Per (b,h): 131x131 output, K=256. 32x32 tile per block, 2x2 per thread.
// ---------------------------------------------------------------------------
__global__ __launch_bounds__(256) void edge_kernel(
    const float* __restrict__ Gq, const float* __restrict__ Gk,
    float* __restrict__ edge)
{
    const int bh = blockIdx.z;
    const int b = bh >> 2, h = bh & 3;
    const int x0 = blockIdx.y * 32, y0 = blockIdx.x * 32;
    __shared__ float Qs[32][17];
    __shared__ float Ks[32][17];
    const int tid = threadIdx.x;
    const int tx = tid & 15, ty = tid >> 4;
    float acc[2][2] = {};
    const float* gq = Gq + (size_t)b * Nn * OUTF + h * Dd;
    const float* gk = Gk + (size_t)b * Nn * OUTF + h * Dd;

    for (int k0 = 0; k0 < Dd; k0 += 16) {
        const int j = tid & 15, i = tid >> 4;
        #pragma unroll
        for (int r = 0; r < 2; ++r) {
            const int xx = x0 + i + 16 * r;
            Qs[i + 16 * r][j] = (xx < Nn) ? gq[(size_t)xx * OUTF + k0 + j] : 0.f;
            const int yy = y0 + i + 16 * r;
            Ks[i + 16 * r][j] = (yy < Nn) ? gk[(size_t)yy * OUTF + k0 + j] : 0.f;
        }
        __syncthreads();
        #pragma unroll
        for (int kk = 0; kk < 16; ++kk) {
            const float q0 = Qs[ty][kk], q1 = Qs[ty + 16][kk];
            const float k0v = Ks[tx][kk], k1v = Ks[tx + 16][kk];
            acc[0][0] += q0 * k0v; acc[0][1] += q0 * k1v;
            acc[1][0] += q1 * k0v; acc[1][1] += q1 * k1v;
        }
        __syncthreads();
    }

    #pragma unroll
    for (int r = 0; r < 2; ++r)
        #pragma unroll
        for (int c = 0; c < 2; ++c) {
            const int x = x0 + ty + 16 * r, y = y0 + tx + 16 * c;
            if (x < Nn && y < Nn) {
                const float v = 1.f / (1.f + expf(-acc[r][c] * (1.f / 16.f)));
                edge[((size_t)bh * Nn + x) * Nn + y] = v;
            }
        }
}

// ---------------------------------------------------------------------------
// d_inv[b,h,x] = rsqrt( 1 + sum_y adj[b,x,y] * edge[b,h,x,y] )
// One wave per (b,h,x) row.
// ---------------------------------------------------------------------------
__global__ __launch_bounds__(256) void rowsum_kernel(
    const float* __restrict__ adj, const float* __restrict__ edge,
    float* __restrict__ dinv)
{
    const int wid = (blockIdx.x * 256 + threadIdx.x) >> 6;
    const int lane = threadIdx.x & 63;
    const int x = wid % Nn;
    const int bh = wid / Nn;
    const int b = bh >> 2;
    const float* arow = adj + ((size_t)b * Nn + x) * Nn;
    const float* erow = edge + ((size_t)bh * Nn + x) * Nn;
    float s = 0.f;
    for (int y = lane; y < Nn; y += 64) s += arow[y] * erow[y];
    #pragma unroll
    for (int off = 32; off; off >>= 1) s += __shfl_xor(s, off);
    if (lane == 0) dinv[wid] = rsqrtf(s + 1.f);
}

// ---------------------------------------------------------------------------
// Aggregation: Gout[b,x,h*256+d] = dinv[bh,x] * sum_y w[x][y]*Graw[b,y,h*256+d]
//   w[x][y] = (adj[b,x,y]*edge[bh,x,y] + (x==y)) * dinv[bh,y] * att[b,y]
// Per (b,h): out 131x256, K=131. 32x64 tile/block, thread 2x4.
// ---------------------------------------------------------------------------
__global__ __launch_bounds__(256) void agg_kernel(
    const float* __restrict__ adj, const float* __restrict__ edge,
    const float* __restrict__ dinv, const float* __restrict__ att,
    const float* __restrict__ Graw, float* __restrict__ Gout)
{
    const int bh = blockIdx.z;
    const int b = bh >> 2, h = bh & 3;
    const int x0 = blockIdx.y * 32;
    const int d0 = blockIdx.x * 64;
    __shared__ float Wt[32][17];
    __shared__ float Gs[16][64];
    const int tid = threadIdx.x;
    const int tx = tid & 15, ty = tid >> 4;
    float acc[2][4] = {};
    const float* amat = adj + (size_t)b * Nn * Nn;
    const float* emat = edge + (size_t)bh * Nn * Nn;
    const float* graw = Graw + (size_t)b * Nn * OUTF + h * Dd + d0;
    const float* dv = dinv + (size_t)bh * Nn;
    const float* av = att + (size_t)b * Nn;

    for (int y0 = 0; y0 < Nn; y0 += 16) {
        const int j = tid & 15, i = tid >> 4;
        #pragma unroll
        for (int r = 0; r < 2; ++r) {
            const int x = x0 + i + 16 * r, y = y0 + j;
            float w = 0.f;
            if (x < Nn && y < Nn) {
                w = amat[(size_t)x * Nn + y] * emat[(size_t)x * Nn + y];
                if (x == y) w += 1.f;
                w *= dv[y] * av[y];
            }
            Wt[i + 16 * r][j] = w;
        }
        const int gc = tid & 63, gr = tid >> 6;
        #pragma unroll
        for (int s = 0; s < 4; ++s) {
            const int y = y0 + gr + 4 * s;
            Gs[gr + 4 * s][gc] = (y < Nn) ? graw[(size_t)y * OUTF + gc] : 0.f;
        }
        __syncthreads();
        #pragma unroll
        for (int kk = 0; kk < 16; ++kk) {
            const float w0 = Wt[ty][kk], w1 = Wt[ty + 16][kk];
            float g[4];
            #pragma unroll
            for (int c = 0; c < 4; ++c) g[c] = Gs[kk][tx + 16 * c];
            #pragma unroll
            for (int c = 0; c < 4; ++c) {
                acc[0][c] += w0 * g[c];
                acc[1][c] += w1 * g[c];
            }
        }
        __syncthreads();
    }

    #pragma unroll
    for (int r = 0; r < 2; ++r) {
        const int x = x0 + ty + 16 * r;
        if (x < Nn) {
            const float di = dv[x];
            #pragma unroll
            for (int c = 0; c < 4; ++c)
                Gout[((size_t)b * Nn + x) * OUTF + h * Dd + d0 + tx + 16 * c] =
                    acc[r][c] * di;
        }
    }
}

// ---------------------------------------------------------------------------
// global_node[b,o] = lrelu(b_gs + sum_n W_gs[n]*Gout[b,n,o]); build Z_in.
// ---------------------------------------------------------------------------
__global__ __launch_bounds__(256) void gn_kernel(
    const float* __restrict__ Gout, const float* __restrict__ Wgs,
    const float* __restrict__ bgs, const float* __restrict__ Tx,
    float* __restrict__ Zin)
{
    __shared__ float wgs[Nn];
    if (threadIdx.x < Nn) wgs[threadIdx.x] = Wgs[threadIdx.x];
    __syncthreads();
    const int idx = blockIdx.x * 256 + threadIdx.x;
    const int b = idx >> 10, o = idx & 1023;
    float s = bgs[0];
    const float* g = Gout + (size_t)b * Nn * OUTF + o;
    for (int n = 0; n < Nn; ++n) s += wgs[n] * g[(size_t)n * OUTF];
    Zin[(size_t)b * 2048 + o] = LRELU(s);
    Zin[(size_t)b * 2048 + 1024 + o] = Tx[(size_t)b * OUTF + o];
}

// ---------------------------------------------------------------------------
extern "C" void kernel_launch(void* const* d_in, const int* in_sizes, int n_in,
                              void* d_out, int out_size, void* d_ws, size_t ws_size,
                              hipStream_t stream) {
    const float* tab  = (const float*)d_in[0];
    const float* node = (const float*)d_in[1];
    const float* adj  = (const float*)d_in[2];
    const float* W_gx = (const float*)d_in[3];
    const float* b_gx = (const float*)d_in[4];
    const float* W_tx = (const float*)d_in[5];
    const float* b_tx = (const float*)d_in[6];
    const float* W_gk = (const float*)d_in[7];
    const float* W_tq = (const float*)d_in[8];
    const float* W_gq = (const float*)d_in[9];
    const float* W_gs = (const float*)d_in[10];
    const float* b_gs = (const float*)d_in[11];
    const float* W_zx = (const float*)d_in[12];
    const float* b_zx = (const float*)d_in[13];

    const size_t GX_ELEMS = (size_t)Bb * Nn * OUTF;   // 34,340,864
    float* out   = (float*)d_out;
    float* o_GX  = out;
    float* o_TX  = o_GX + GX_ELEMS;
    float* o_ZX  = o_TX + (size_t)Bb * OUTF;
    float* o_ATT = o_ZX + (size_t)Bb * OUTF;
    float* o_EDG = o_ATT + (size_t)Bb * Nn;

    float* ws     = (float*)d_ws;
    float* w_Graw = ws;
    float* w_Gk   = w_Graw + GX_ELEMS;
    float* w_Gq   = w_Gk + GX_ELEMS;
    float* w_Tq   = w_Gq + GX_ELEMS;
    float* w_dinv = w_Tq + (size_t)Bb * OUTF;
    float* w_Zin  = w_dinv + (size_t)Bb * Hh * Nn;

    const dim3 blk(256);
    const int M_NODE = Bb * Nn;  // 33536 = 64*524

    // Tabular GEMMs
    gemm_aw<<<dim3(16, 4), blk, 0, stream>>>(tab, W_tx, b_tx, o_TX, Bb, INF_, OUTF);
    gemm_aw<<<dim3(16, 4), blk, 0, stream>>>(tab, W_tq, nullptr, w_Tq, Bb, INF_, OUTF);
    // Node GEMMs
    gemm_aw<<<dim3(16, 524), blk, 0, stream>>>(node, W_gx, b_gx, w_Graw, M_NODE, INF_, OUTF);
    gemm_aw<<<dim3(16, 524), blk, 0, stream>>>(node, W_gk, nullptr, w_Gk, M_NODE, INF_, OUTF);
    gemm_aw<<<dim3(16, 524), blk, 0, stream>>>(node, W_gq, nullptr, w_Gq, M_NODE, INF_, OUTF);
    // Node attention (softmax over N) -> d_out att region (values = p+1)
    nodeatt_kernel<<<dim3(Bb), blk, 0, stream>>>(w_Tq, w_Gk, o_ATT);
    // Edge attention -> d_out edge region
    edge_kernel<<<dim3(5, 5, Bb * Hh), blk, 0, stream>>>(w_Gq, w_Gk, o_EDG);
    // Degree normalization
    rowsum_kernel<<<dim3((Bb * Hh * Nn * 64) / 256), blk, 0, stream>>>(adj, o_EDG, w_dinv);
    // Aggregation -> d_out G_X
    agg_kernel<<<dim3(4, 5, Bb * Hh), blk, 0, stream>>>(adj, o_EDG, w_dinv, o_ATT, w_Graw, o_GX);
    // Graph summary + Z_in build
    gn_kernel<<<dim3((Bb * OUTF) / 256), blk, 0, stream>>>(o_GX, W_gs, b_gs, o_TX, w_Zin);
    // Final Z GEMM
    gemm_aw<<<dim3(16, 4), blk, 0, stream>>>(w_Zin, W_zx, b_zx, o_ZX, Bb, 2 * OUTF, OUTF);
}

// Round 2
// 933.135 us; speedup vs baseline: 3.0603x; 3.0603x over previous
//
#include <hip/hip_runtime.h>
#include <hip/hip_bf16.h>
#include <math.h>

// Dynamic_MHGCN_FusionLayer: B=256, N=131, IN=512, OUT=1024, H=4, D=256
// Round 2: bf16 MFMA for node GEMMs (fused 3-in-1) and edge attention.
// Intermediates (Graw|Gk|Gq) stored bf16 in one [M][3072] buffer.

#define LRELU(x) ((x) > 0.f ? (x) : 0.01f * (x))

constexpr int Bb = 256;
constexpr int Nn = 131;
constexpr int INF_ = 512;
constexpr int OUTF = 1024;
constexpr int Hh = 4;
constexpr int Dd = 256;
constexpr int OC = 3072;           // Graw(0..1023) | Gk(1024..2047) | Gq(2048..3071)

typedef __attribute__((ext_vector_type(8))) short bf16x8;
typedef __attribute__((ext_vector_type(4))) float f32x4;

__device__ __forceinline__ float bf2f(short s) {
    union { float f; unsigned u; } c;
    c.u = ((unsigned)(unsigned short)s) << 16;
    return c.f;
}

__device__ __forceinline__ void gload_lds16(const void* g, void* lds) {
    __builtin_amdgcn_global_load_lds(
        (const __attribute__((address_space(1))) void*)g,
        (__attribute__((address_space(3))) void*)lds, 16, 0, 0);
}

// ---------------------------------------------------------------------------
// fp32 -> bf16 conversion: node_feats and the packed weight matrix Wcat.
// ---------------------------------------------------------------------------
__global__ __launch_bounds__(256) void convert_kernel(
    const float* __restrict__ node, const float* __restrict__ Wgx,
    const float* __restrict__ Wgk, const float* __restrict__ Wgq,
    __hip_bfloat16* __restrict__ node_bf, __hip_bfloat16* __restrict__ Wcat)
{
    const size_t NE = (size_t)Bb * Nn * INF_ / 4;  // float4 groups in node
    const size_t WE = (size_t)OC * INF_ / 4;       // float4 groups in Wcat
    for (size_t i = (size_t)blockIdx.x * 256 + threadIdx.x; i < NE + WE;
         i += (size_t)gridDim.x * 256) {
        if (i < NE) {
            const float4 v = ((const float4*)node)[i];
            __hip_bfloat16* o = node_bf + i * 4;
            o[0] = __float2bfloat16(v.x); o[1] = __float2bfloat16(v.y);
            o[2] = __float2bfloat16(v.z); o[3] = __float2bfloat16(v.w);
        } else {
            const size_t j = i - NE;                 // group idx in Wcat
            const size_t which = j / (1024 * INF_ / 4);
            const float* src = (which == 0) ? Wgx : (which == 1 ? Wgk : Wgq);
            const size_t srcj = j - which * (1024 * INF_ / 4);
            const float4 v = ((const float4*)src)[srcj];
            __hip_bfloat16* o = Wcat + j * 4;
            o[0] = __float2bfloat16(v.x); o[1] = __float2bfloat16(v.y);
            o[2] = __float2bfloat16(v.z); o[3] = __float2bfloat16(v.w);
        }
    }
}

// ---------------------------------------------------------------------------
// Fused node GEMM (bf16 MFMA): Gcat[m][o] = lrelu(A[m][:] . Wcat[o][:] + bias)
// bias = b_gx[o] for o<1024 else 0. 128x128 tile, BK=32, 4 waves (2x2),
// each wave 64x64 = 4x4 frags of mfma_f32_16x16x32_bf16. m97-style staging.
// M=33536 (%128==0), OC=3072 (%128==0), K=512.
// ---------------------------------------------------------------------------
__global__ __launch_bounds__(256) void gemm_node_mfma(
    const __hip_bfloat16* __restrict__ A, const __hip_bfloat16* __restrict__ W,
    const float* __restrict__ bias_gx, __hip_bfloat16* __restrict__ Gcat)
{
    __shared__ short As[128 * 32];
    __shared__ short Bs[128 * 32];
    const int tid = threadIdx.x;
    const int wave = tid >> 6, lane = tid & 63;
    const int m0 = blockIdx.y * 128, o0 = blockIdx.x * 128;
    const int wr = wave >> 1, wc = wave & 1;

    f32x4 acc[4][4] = {};
    const short* Asrc = (const short*)A;
    const short* Wsrc = (const short*)W;
    const int lr = lane >> 2;          // row within 16-row chunk
    const int lcs = (lane & 3) * 8;    // k offset in shorts (16B granule)

    for (int k0 = 0; k0 < INF_; k0 += 32) {
        #pragma unroll
        for (int t = 0; t < 2; ++t) {
            const int c = wave * 2 + t;  // chunk 0..7 (16 rows each)
            gload_lds16(Asrc + (size_t)(m0 + c * 16 + lr) * INF_ + k0 + lcs,
                        &As[c * 512]);
            gload_lds16(Wsrc + (size_t)(o0 + c * 16 + lr) * INF_ + k0 + lcs,
                        &Bs[c * 512]);
        }
        __syncthreads();
        bf16x8 af[4], bfr[4];
        #pragma unroll
        for (int i = 0; i < 4; ++i) {
            af[i]  = *(const bf16x8*)&As[(wr * 64 + i * 16 + (lane & 15)) * 32 + (lane >> 4) * 8];
            bfr[i] = *(const bf16x8*)&Bs[(wc * 64 + i * 16 + (lane & 15)) * 32 + (lane >> 4) * 8];
        }
        #pragma unroll
        for (int mi = 0; mi < 4; ++mi)
            #pragma unroll
            for (int ni = 0; ni < 4; ++ni)
                acc[mi][ni] = __builtin_amdgcn_mfma_f32_16x16x32_bf16(
                    af[mi], bfr[ni], acc[mi][ni], 0, 0, 0);
        __syncthreads();
    }

    const int cc = lane & 15;
    const int rg = (lane >> 4) * 4;
    #pragma unroll
    for (int mi = 0; mi < 4; ++mi) {
        #pragma unroll
        for (int ni = 0; ni < 4; ++ni) {
            const int o = o0 + wc * 64 + ni * 16 + cc;
            const float badd = (o < OUTF) ? bias_gx[o] : 0.f;
            #pragma unroll
            for (int r = 0; r < 4; ++r) {
                const int m = m0 + wr * 64 + mi * 16 + rg + r;
                float v = acc[mi][ni][r] + badd;
                v = LRELU(v);
                Gcat[(size_t)m * OC + o] = __float2bfloat16(v);
            }
        }
    }
}

// ---------------------------------------------------------------------------
// Edge attention (bf16 MFMA): per (b,h), S = Gq_h . Gk_h^T, 131x131, K=256.
// 64x64 tile per block, grid (3,3,B*H). sigmoid(S/16) -> edge (fp32 out).
// ---------------------------------------------------------------------------
__global__ __launch_bounds__(256) void edge_mfma(
    const __hip_bfloat16* __restrict__ Gcat, float* __restrict__ edge)
{
    const int bh = blockIdx.z;
    const int b = bh >> 2, h = bh & 3;
    const int x0 = blockIdx.y * 64, y0 = blockIdx.x * 64;
    __shared__ short Qs[64 * 32];
    __shared__ short Ks[64 * 32];
    const int tid = threadIdx.x;
    const int wave = tid >> 6, lane = tid & 63;
    const int wr = wave >> 1, wc = wave & 1;
    f32x4 acc[2][2] = {};
    const short* qbase = (const short*)Gcat + (size_t)b * Nn * OC + 2048 + h * Dd;
    const short* kbase = (const short*)Gcat + (size_t)b * Nn * OC + 1024 + h * Dd;
    const int lr = lane >> 2, lcs = (lane & 3) * 8;

    for (int k0 = 0; k0 < Dd; k0 += 32) {
        {
            const int c = wave;  // 4 chunks of 16 rows per tile
            int xr = x0 + c * 16 + lr; if (xr > Nn - 1) xr = Nn - 1;
            gload_lds16(qbase + (size_t)xr * OC + k0 + lcs, &Qs[c * 512]);
            int yr = y0 + c * 16 + lr; if (yr > Nn - 1) yr = Nn - 1;
            gload_lds16(kbase + (size_t)yr * OC + k0 + lcs, &Ks[c * 512]);
        }
        __syncthreads();
        bf16x8 qf[2], kf[2];
        #pragma unroll
        for (int i = 0; i < 2; ++i) {
            qf[i] = *(const bf16x8*)&Qs[(wr * 32 + i * 16 + (lane & 15)) * 32 + (lane >> 4) * 8];
            kf[i] = *(const bf16x8*)&Ks[(wc * 32 + i * 16 + (lane & 15)) * 32 + (lane >> 4) * 8];
        }
        #pragma unroll
        for (int mi = 0; mi < 2; ++mi)
            #pragma unroll
            for (int ni = 0; ni < 2; ++ni)
                acc[mi][ni] = __builtin_amdgcn_mfma_f32_16x16x32_bf16(
                    qf[mi], kf[ni], acc[mi][ni], 0, 0, 0);
        __syncthreads();
    }

    const int cc = lane & 15;
    const int rg = (lane >> 4) * 4;
    #pragma unroll
    for (int mi = 0; mi < 2; ++mi)
        #pragma unroll
        for (int ni = 0; ni < 2; ++ni)
            #pragma unroll
            for (int r = 0; r < 4; ++r) {
                const int x = x0 + wr * 32 + mi * 16 + rg + r;
                const int y = y0 + wc * 32 + ni * 16 + cc;
                if (x < Nn && y < Nn)
                    edge[((size_t)bh * Nn + x) * Nn + y] =
                        1.f / (1.f + expf(-acc[mi][ni][r] * (1.f / 16.f)));
            }
}

// ---------------------------------------------------------------------------
// Generic fp32 tiled GEMM (kept for the small tabular / Z GEMMs).
// C[m,o] = lrelu( sum_k A[m,k]*W[o,k] + bias[o] ). M%64==0, K%16==0, O%64==0.
// ---------------------------------------------------------------------------
__global__ __launch_bounds__(256) void gemm_aw(
    const float* __restrict__ A, const float* __restrict__ W,
    const float* __restrict__ bias, float* __restrict__ C,
    int M, int K, int O)
{
    __shared__ float As[16][68];
    __shared__ float Ws[16][68];
    const int tid = threadIdx.x;
    const int tx = tid & 15;
    const int ty = tid >> 4;
    const int m0 = blockIdx.y * 64;
    const int o0 = blockIdx.x * 64;

    float acc[4][4] = {};

    for (int k0 = 0; k0 < K; k0 += 16) {
        const int j = tid & 15;
        const int i = tid >> 4;
        #pragma unroll
        for (int r = 0; r < 4; ++r)
            As[j][i + 16 * r] = A[(size_t)(m0 + i + 16 * r) * K + k0 + j];
        #pragma unroll
        for (int r = 0; r < 4; ++r)
            Ws[j][i + 16 * r] = W[(size_t)(o0 + i + 16 * r) * K + k0 + j];
        __syncthreads();
        #pragma unroll
        for (int kk = 0; kk < 16; ++kk) {
            const float4 av = *(const float4*)&As[kk][ty * 4];
            const float4 wv = *(const float4*)&Ws[kk][tx * 4];
            const float a[4] = {av.x, av.y, av.z, av.w};
            const float w[4] = {wv.x, wv.y, wv.z, wv.w};
            #pragma unroll
            for (int r = 0; r < 4; ++r)
                #pragma unroll
                for (int c = 0; c < 4; ++c)
                    acc[r][c] += a[r] * w[c];
        }
        __syncthreads();
    }

    #pragma unroll
    for (int r = 0; r < 4; ++r) {
        const int m = m0 + ty * 4 + r;
        const int o = o0 + tx * 4;
        float4 v;
        float* vp = (float*)&v;
        #pragma unroll
        for (int c = 0; c < 4; ++c) {
            float t = acc[r][c] + (bias ? bias[o + c] : 0.f);
            vp[c] = LRELU(t);
        }
        *(float4*)&C[(size_t)m * O + o] = v;
    }
}

// ---------------------------------------------------------------------------
// node_att softmax: s[b,n] = (1/32) * Tq[b,:] . Gk[b,n,:]; softmax over n; +1.
// ---------------------------------------------------------------------------
__global__ __launch_bounds__(256) void nodeatt_kernel(
    const float* __restrict__ Tq, const __hip_bfloat16* __restrict__ Gcat,
    float* __restrict__ att)
{
    const int b = blockIdx.x;
    __shared__ float tq[OUTF];
    __shared__ float sc[136];
    const int tid = threadIdx.x;
    for (int o = tid; o < OUTF; o += 256) tq[o] = Tq[(size_t)b * OUTF + o];
    __syncthreads();

    const int wave = tid >> 6, lane = tid & 63;
    for (int n = wave; n < Nn; n += 4) {
        const short4* gk = (const short4*)((const short*)Gcat + ((size_t)b * Nn + n) * OC + 1024);
        float s = 0.f;
        for (int o4 = lane; o4 < 256; o4 += 64) {
            const short4 v = gk[o4];
            s += tq[o4 * 4 + 0] * bf2f(v.x) + tq[o4 * 4 + 1] * bf2f(v.y)
               + tq[o4 * 4 + 2] * bf2f(v.z) + tq[o4 * 4 + 3] * bf2f(v.w);
        }
        #pragma unroll
        for (int off = 32; off; off >>= 1) s += __shfl_xor(s, off);
        if (lane == 0) sc[n] = s * (1.f / 32.f);
    }
    __syncthreads();

    if (tid < 64) {
        const float v1 = sc[lane];
        const float v2 = sc[lane + 64];
        const float v3 = (lane < 3) ? sc[lane + 128] : -1e30f;
        float m = fmaxf(fmaxf(v1, v2), v3);
        #pragma unroll
        for (int off = 32; off; off >>= 1) m = fmaxf(m, __shfl_xor(m, off));
        const float e1 = expf(v1 - m);
        const float e2 = expf(v2 - m);
        const float e3 = (lane < 3) ? expf(v3 - m) : 0.f;
        float s = e1 + e2 + e3;
        #pragma unroll
        for (int off = 32; off; off >>= 1) s += __shfl_xor(s, off);
        const float inv = 1.f / s;
        float* ab = att + (size_t)b * Nn;
        ab[lane] = e1 * inv + 1.f;
        ab[lane + 64] = e2 * inv + 1.f;
        if (lane < 3) ab[lane + 128] = e3 * inv + 1.f;
    }
}

// ---------------------------------------------------------------------------
// d_inv[bh,x] = rsqrt( 1 + sum_y adj[b,x,y]*edge[bh,x,y] ). One wave per row.
// ---------------------------------------------------------------------------
__global__ __launch_bounds__(256) void rowsum_kernel(
    const float* __restrict__ adj, const float* __restrict__ edge,
    float* __restrict__ dinv)
{
    const int wid = (blockIdx.x * 256 + threadIdx.x) >> 6;
    const int lane = threadIdx.x & 63;
    const int x = wid % Nn;
    const int bh = wid / Nn;
    const int b = bh >> 2;
    const float* arow = adj + ((size_t)b * Nn + x) * Nn;
    const float* erow = edge + ((size_t)bh * Nn + x) * Nn;
    float s = 0.f;
    for (int y = lane; y < Nn; y += 64) s += arow[y] * erow[y];
    #pragma unroll
    for (int off = 32; off; off >>= 1) s += __shfl_xor(s, off);
    if (lane == 0) dinv[wid] = rsqrtf(s + 1.f);
}

// ---------------------------------------------------------------------------
// Aggregation: Gout[b,x,h*256+d] = dinv[bh,x] * sum_y w[x][y]*Graw[b,y,h*256+d]
//   w[x][y] = (adj*edge + (x==y)) * dinv[bh,y] * att[b,y]
// ---------------------------------------------------------------------------
__global__ __launch_bounds__(256) void agg_kernel(
    const float* __restrict__ adj, const float* __restrict__ edge,
    const float* __restrict__ dinv, const float* __restrict__ att,
    const __hip_bfloat16* __restrict__ Gcat, float* __restrict__ Gout)
{
    const int bh = blockIdx.z;
    const int b = bh >> 2, h = bh & 3;
    const int x0 = blockIdx.y * 32;
    const int d0 = blockIdx.x * 64;
    __shared__ float Wt[32][17];
    __shared__ float Gs[16][64];
    const int tid = threadIdx.x;
    const int tx = tid & 15, ty = tid >> 4;
    float acc[2][4] = {};
    const float* amat = adj + (size_t)b * Nn * Nn;
    const float* emat = edge + (size_t)bh * Nn * Nn;
    const short* graw = (const short*)Gcat + (size_t)b * Nn * OC + h * Dd + d0;
    const float* dv = dinv + (size_t)bh * Nn;
    const float* av = att + (size_t)b * Nn;

    for (int y0 = 0; y0 < Nn; y0 += 16) {
        const int j = tid & 15, i = tid >> 4;
        #pragma unroll
        for (int r = 0; r < 2; ++r) {
            const int x = x0 + i + 16 * r, y = y0 + j;
            float w = 0.f;
            if (x < Nn && y < Nn) {
                w = amat[(size_t)x * Nn + y] * emat[(size_t)x * Nn + y];
                if (x == y) w += 1.f;
                w *= dv[y] * av[y];
            }
            Wt[i + 16 * r][j] = w;
        }
        const int gc = tid & 63, gr = tid >> 6;
        #pragma unroll
        for (int s = 0; s < 4; ++s) {
            const int y = y0 + gr + 4 * s;
            Gs[gr + 4 * s][gc] = (y < Nn) ? bf2f(graw[(size_t)y * OC + gc]) : 0.f;
        }
        __syncthreads();
        #pragma unroll
        for (int kk = 0; kk < 16; ++kk) {
            const float w0 = Wt[ty][kk], w1 = Wt[ty + 16][kk];
            float g[4];
            #pragma unroll
            for (int c = 0; c < 4; ++c) g[c] = Gs[kk][tx + 16 * c];
            #pragma unroll
            for (int c = 0; c < 4; ++c) {
                acc[0][c] += w0 * g[c];
                acc[1][c] += w1 * g[c];
            }
        }
        __syncthreads();
    }

    #pragma unroll
    for (int r = 0; r < 2; ++r) {
        const int x = x0 + ty + 16 * r;
        if (x < Nn) {
            const float di = dv[x];
            #pragma unroll
            for (int c = 0; c < 4; ++c)
                Gout[((size_t)b * Nn + x) * OUTF + h * Dd + d0 + tx + 16 * c] =
                    acc[r][c] * di;
        }
    }
}

// ---------------------------------------------------------------------------
// global_node[b,o] = lrelu(b_gs + sum_n W_gs[n]*Gout[b,n,o]); build Z_in.
// ---------------------------------------------------------------------------
__global__ __launch_bounds__(256) void gn_kernel(
    const float* __restrict__ Gout, const float* __restrict__ Wgs,
    const float* __restrict__ bgs, const float* __restrict__ Tx,
    float* __restrict__ Zin)
{
    __shared__ float wgs[Nn];
    if (threadIdx.x < Nn) wgs[threadIdx.x] = Wgs[threadIdx.x];
    __syncthreads();
    const int idx = blockIdx.x * 256 + threadIdx.x;
    const int b = idx >> 10, o = idx & 1023;
    float s = bgs[0];
    const float* g = Gout + (size_t)b * Nn * OUTF + o;
    for (int n = 0; n < Nn; ++n) s += wgs[n] * g[(size_t)n * OUTF];
    Zin[(size_t)b * 2048 + o] = LRELU(s);
    Zin[(size_t)b * 2048 + 1024 + o] = Tx[(size_t)b * OUTF + o];
}

// ---------------------------------------------------------------------------
extern "C" void kernel_launch(void* const* d_in, const int* in_sizes, int n_in,
                              void* d_out, int out_size, void* d_ws, size_t ws_size,
                              hipStream_t stream) {
    const float* tab  = (const float*)d_in[0];
    const float* node = (const float*)d_in[1];
    const float* adj  = (const float*)d_in[2];
    const float* W_gx = (const float*)d_in[3];
    const float* b_gx = (const float*)d_in[4];
    const float* W_tx = (const float*)d_in[5];
    const float* b_tx = (const float*)d_in[6];
    const float* W_gk = (const float*)d_in[7];
    const float* W_tq = (const float*)d_in[8];
    const float* W_gq = (const float*)d_in[9];
    const float* W_gs = (const float*)d_in[10];
    const float* b_gs = (const float*)d_in[11];
    const float* W_zx = (const float*)d_in[12];
    const float* b_zx = (const float*)d_in[13];

    const size_t GX_ELEMS = (size_t)Bb * Nn * OUTF;   // 34,340,864
    const int M_NODE = Bb * Nn;                       // 33536

    float* out   = (float*)d_out;
    float* o_GX  = out;
    float* o_TX  = o_GX + GX_ELEMS;
    float* o_ZX  = o_TX + (size_t)Bb * OUTF;
    float* o_ATT = o_ZX + (size_t)Bb * OUTF;
    float* o_EDG = o_ATT + (size_t)Bb * Nn;

    // workspace: bf16 sections first (2B), then fp32 sections
    __hip_bfloat16* wb      = (__hip_bfloat16*)d_ws;
    __hip_bfloat16* w_nodeb = wb;                                        // 33536*512
    __hip_bfloat16* w_Wcat  = w_nodeb + (size_t)M_NODE * INF_;           // 3072*512
    __hip_bfloat16* w_Gcat  = w_Wcat + (size_t)OC * INF_;                // 33536*3072
    float* wf     = (float*)(w_Gcat + (size_t)M_NODE * OC);
    float* w_Tq   = wf;
    float* w_dinv = w_Tq + (size_t)Bb * OUTF;
    float* w_Zin  = w_dinv + (size_t)Bb * Hh * Nn;

    const dim3 blk(256);

    // 0. fp32 -> bf16 conversions
    convert_kernel<<<dim3(2048), blk, 0, stream>>>(node, W_gx, W_gk, W_gq,
                                                   w_nodeb, w_Wcat);
    // 1. tabular GEMMs (fp32, tiny)
    gemm_aw<<<dim3(16, 4), blk, 0, stream>>>(tab, W_tx, b_tx, o_TX, Bb, INF_, OUTF);
    gemm_aw<<<dim3(16, 4), blk, 0, stream>>>(tab, W_tq, nullptr, w_Tq, Bb, INF_, OUTF);
    // 2. fused node GEMM -> Gcat bf16 [33536][3072]
    gemm_node_mfma<<<dim3(OC / 128, M_NODE / 128), blk, 0, stream>>>(
        w_nodeb, w_Wcat, b_gx, w_Gcat);
    // 3. node attention -> o_ATT (values = softmax+1)
    nodeatt_kernel<<<dim3(Bb), blk, 0, stream>>>(w_Tq, w_Gcat, o_ATT);
    // 4. edge attention (MFMA) -> o_EDG
    edge_mfma<<<dim3(3, 3, Bb * Hh), blk, 0, stream>>>(w_Gcat, o_EDG);
    // 5. degree normalization
    rowsum_kernel<<<dim3((Bb * Hh * Nn * 64) / 256), blk, 0, stream>>>(adj, o_EDG, w_dinv);
    // 6. aggregation -> o_GX
    agg_kernel<<<dim3(4, 5, Bb * Hh), blk, 0, stream>>>(adj, o_EDG, w_dinv, o_ATT,
                                                        w_Gcat, o_GX);
    // 7. graph summary + Z_in build
    gn_kernel<<<dim3((Bb * OUTF) / 256), blk, 0, stream>>>(o_GX, W_gs, b_gs, o_TX, w_Zin);
    // 8. final Z GEMM
    gemm_aw<<<dim3(16, 4), blk, 0, stream>>>(w_Zin, W_zx, b_zx, o_ZX, Bb, 2 * OUTF, OUTF);
}

// Round 3
// 856.954 us; speedup vs baseline: 3.3323x; 1.0889x over previous
//
#include <hip/hip_runtime.h>
#include <hip/hip_bf16.h>
#include <math.h>

// Dynamic_MHGCN_FusionLayer: B=256, N=131, IN=512, OUT=1024, H=4, D=256
// Round 3: MFMA aggregation path. edge+rowsum+weight-build fused per (b,h);
// Graw transposed once globally; agg is a bf16 MFMA batched GEMM with all
// normalization (dinv_x, dinv_y, att_y, self-loop) folded into Wb.

#define LRELU(x) ((x) > 0.f ? (x) : 0.01f * (x))

constexpr int Bb = 256;
constexpr int Nn = 131;
constexpr int INF_ = 512;
constexpr int OUTF = 1024;
constexpr int Hh = 4;
constexpr int Dd = 256;
constexpr int OC = 3072;   // Graw(0..1023) | Gk(1024..2047) | Gq(2048..3071)
constexpr int YP = 168;    // padded y-stride (shorts) for Wb / GrawT rows
constexpr int KAGG = 160;  // padded K (y) for aggregation GEMM
constexpr int XP = 144;    // padded x rows for Wb

typedef __attribute__((ext_vector_type(8))) short bf16x8;
typedef __attribute__((ext_vector_type(4))) float f32x4;

__device__ __forceinline__ float bf2f(short s) {
    union { float f; unsigned u; } c;
    c.u = ((unsigned)(unsigned short)s) << 16;
    return c.f;
}

__device__ __forceinline__ void gload_lds16(const void* g, void* lds) {
    __builtin_amdgcn_global_load_lds(
        (const __attribute__((address_space(1))) void*)g,
        (__attribute__((address_space(3))) void*)lds, 16, 0, 0);
}

// ---------------------------------------------------------------------------
// fp32 -> bf16 conversion: node_feats and the packed weight matrix Wcat.
// ---------------------------------------------------------------------------
__global__ __launch_bounds__(256) void convert_kernel(
    const float* __restrict__ node, const float* __restrict__ Wgx,
    const float* __restrict__ Wgk, const float* __restrict__ Wgq,
    __hip_bfloat16* __restrict__ node_bf, __hip_bfloat16* __restrict__ Wcat)
{
    const size_t NE = (size_t)Bb * Nn * INF_ / 4;
    const size_t WE = (size_t)OC * INF_ / 4;
    for (size_t i = (size_t)blockIdx.x * 256 + threadIdx.x; i < NE + WE;
         i += (size_t)gridDim.x * 256) {
        if (i < NE) {
            const float4 v = ((const float4*)node)[i];
            __hip_bfloat16* o = node_bf + i * 4;
            o[0] = __float2bfloat16(v.x); o[1] = __float2bfloat16(v.y);
            o[2] = __float2bfloat16(v.z); o[3] = __float2bfloat16(v.w);
        } else {
            const size_t j = i - NE;
            const size_t which = j / (1024 * INF_ / 4);
            const float* src = (which == 0) ? Wgx : (which == 1 ? Wgk : Wgq);
            const size_t srcj = j - which * (1024 * INF_ / 4);
            const float4 v = ((const float4*)src)[srcj];
            __hip_bfloat16* o = Wcat + j * 4;
            o[0] = __float2bfloat16(v.x); o[1] = __float2bfloat16(v.y);
            o[2] = __float2bfloat16(v.z); o[3] = __float2bfloat16(v.w);
        }
    }
}

// ---------------------------------------------------------------------------
// Fused node GEMM (bf16 MFMA): Gcat[m][o] = lrelu(A[m][:] . Wcat[o][:] + bias)
// ---------------------------------------------------------------------------
__global__ __launch_bounds__(256) void gemm_node_mfma(
    const __hip_bfloat16* __restrict__ A, const __hip_bfloat16* __restrict__ W,
    const float* __restrict__ bias_gx, __hip_bfloat16* __restrict__ Gcat)
{
    __shared__ short As[128 * 32];
    __shared__ short Bs[128 * 32];
    const int tid = threadIdx.x;
    const int wave = tid >> 6, lane = tid & 63;
    const int m0 = blockIdx.y * 128, o0 = blockIdx.x * 128;
    const int wr = wave >> 1, wc = wave & 1;

    f32x4 acc[4][4] = {};
    const short* Asrc = (const short*)A;
    const short* Wsrc = (const short*)W;
    const int lr = lane >> 2;
    const int lcs = (lane & 3) * 8;

    for (int k0 = 0; k0 < INF_; k0 += 32) {
        #pragma unroll
        for (int t = 0; t < 2; ++t) {
            const int c = wave * 2 + t;
            gload_lds16(Asrc + (size_t)(m0 + c * 16 + lr) * INF_ + k0 + lcs,
                        &As[c * 512]);
            gload_lds16(Wsrc + (size_t)(o0 + c * 16 + lr) * INF_ + k0 + lcs,
                        &Bs[c * 512]);
        }
        __syncthreads();
        bf16x8 af[4], bfr[4];
        #pragma unroll
        for (int i = 0; i < 4; ++i) {
            af[i]  = *(const bf16x8*)&As[(wr * 64 + i * 16 + (lane & 15)) * 32 + (lane >> 4) * 8];
            bfr[i] = *(const bf16x8*)&Bs[(wc * 64 + i * 16 + (lane & 15)) * 32 + (lane >> 4) * 8];
        }
        #pragma unroll
        for (int mi = 0; mi < 4; ++mi)
            #pragma unroll
            for (int ni = 0; ni < 4; ++ni)
                acc[mi][ni] = __builtin_amdgcn_mfma_f32_16x16x32_bf16(
                    af[mi], bfr[ni], acc[mi][ni], 0, 0, 0);
        __syncthreads();
    }

    const int cc = lane & 15;
    const int rg = (lane >> 4) * 4;
    #pragma unroll
    for (int mi = 0; mi < 4; ++mi) {
        #pragma unroll
        for (int ni = 0; ni < 4; ++ni) {
            const int o = o0 + wc * 64 + ni * 16 + cc;
            const float badd = (o < OUTF) ? bias_gx[o] : 0.f;
            #pragma unroll
            for (int r = 0; r < 4; ++r) {
                const int m = m0 + wr * 64 + mi * 16 + rg + r;
                float v = acc[mi][ni][r] + badd;
                v = LRELU(v);
                Gcat[(size_t)m * OC + o] = __float2bfloat16(v);
            }
        }
    }
}

// ---------------------------------------------------------------------------
// Generic fp32 tiled GEMM (small tabular / Z GEMMs).
// ---------------------------------------------------------------------------
__global__ __launch_bounds__(256) void gemm_aw(
    const float* __restrict__ A, const float* __restrict__ W,
    const float* __restrict__ bias, float* __restrict__ C,
    int M, int K, int O)
{
    __shared__ float As[16][68];
    __shared__ float Ws[16][68];
    const int tid = threadIdx.x;
    const int tx = tid & 15;
    const int ty = tid >> 4;
    const int m0 = blockIdx.y * 64;
    const int o0 = blockIdx.x * 64;

    float acc[4][4] = {};

    for (int k0 = 0; k0 < K; k0 += 16) {
        const int j = tid & 15;
        const int i = tid >> 4;
        #pragma unroll
        for (int r = 0; r < 4; ++r)
            As[j][i + 16 * r] = A[(size_t)(m0 + i + 16 * r) * K + k0 + j];
        #pragma unroll
        for (int r = 0; r < 4; ++r)
            Ws[j][i + 16 * r] = W[(size_t)(o0 + i + 16 * r) * K + k0 + j];
        __syncthreads();
        #pragma unroll
        for (int kk = 0; kk < 16; ++kk) {
            const float4 av = *(const float4*)&As[kk][ty * 4];
            const float4 wv = *(const float4*)&Ws[kk][tx * 4];
            const float a[4] = {av.x, av.y, av.z, av.w};
            const float w[4] = {wv.x, wv.y, wv.z, wv.w};
            #pragma unroll
            for (int r = 0; r < 4; ++r)
                #pragma unroll
                for (int c = 0; c < 4; ++c)
                    acc[r][c] += a[r] * w[c];
        }
        __syncthreads();
    }

    #pragma unroll
    for (int r = 0; r < 4; ++r) {
        const int m = m0 + ty * 4 + r;
        const int o = o0 + tx * 4;
        float4 v;
        float* vp = (float*)&v;
        #pragma unroll
        for (int c = 0; c < 4; ++c) {
            float t = acc[r][c] + (bias ? bias[o + c] : 0.f);
            vp[c] = LRELU(t);
        }
        *(float4*)&C[(size_t)m * O + o] = v;
    }
}

// ---------------------------------------------------------------------------
// node_att softmax: s[b,n] = (1/32) * Tq[b,:] . Gk[b,n,:]; softmax over n; +1.
// ---------------------------------------------------------------------------
__global__ __launch_bounds__(256) void nodeatt_kernel(
    const float* __restrict__ Tq, const __hip_bfloat16* __restrict__ Gcat,
    float* __restrict__ att)
{
    const int b = blockIdx.x;
    __shared__ float tq[OUTF];
    __shared__ float sc[136];
    const int tid = threadIdx.x;
    for (int o = tid; o < OUTF; o += 256) tq[o] = Tq[(size_t)b * OUTF + o];
    __syncthreads();

    const int wave = tid >> 6, lane = tid & 63;
    for (int n = wave; n < Nn; n += 4) {
        const short4* gk = (const short4*)((const short*)Gcat + ((size_t)b * Nn + n) * OC + 1024);
        float s = 0.f;
        for (int o4 = lane; o4 < 256; o4 += 64) {
            const short4 v = gk[o4];
            s += tq[o4 * 4 + 0] * bf2f(v.x) + tq[o4 * 4 + 1] * bf2f(v.y)
               + tq[o4 * 4 + 2] * bf2f(v.z) + tq[o4 * 4 + 3] * bf2f(v.w);
        }
        #pragma unroll
        for (int off = 32; off; off >>= 1) s += __shfl_xor(s, off);
        if (lane == 0) sc[n] = s * (1.f / 32.f);
    }
    __syncthreads();

    if (tid < 64) {
        const float v1 = sc[tid];
        const float v2 = sc[tid + 64];
        const float v3 = (tid < 3) ? sc[tid + 128] : -1e30f;
        float m = fmaxf(fmaxf(v1, v2), v3);
        #pragma unroll
        for (int off = 32; off; off >>= 1) m = fmaxf(m, __shfl_xor(m, off));
        const float e1 = expf(v1 - m);
        const float e2 = expf(v2 - m);
        const float e3 = (tid < 3) ? expf(v3 - m) : 0.f;
        float s = e1 + e2 + e3;
        #pragma unroll
        for (int off = 32; off; off >>= 1) s += __shfl_xor(s, off);
        const float inv = 1.f / s;
        float* ab = att + (size_t)b * Nn;
        ab[tid] = e1 * inv + 1.f;
        ab[tid + 64] = e2 * inv + 1.f;
        if (tid < 3) ab[tid + 128] = e3 * inv + 1.f;
    }
}

// ---------------------------------------------------------------------------
// Transpose Graw head-slices: GrawT[bh][d][y] (y padded to 160 with zeros,
// stride YP). 64x64 LDS tiles, grid (4 d-tiles, 3 y-tiles, B*H).
// ---------------------------------------------------------------------------
__global__ __launch_bounds__(256) void transpose_kernel(
    const __hip_bfloat16* __restrict__ Gcat, __hip_bfloat16* __restrict__ GrawT)
{
    const int bh = blockIdx.z, b = bh >> 2, h = bh & 3;
    const int d0 = blockIdx.x * 64, y0 = blockIdx.y * 64;
    __shared__ short Ls[64 * 72];
    const int tid = threadIdx.x;
    const short* src = (const short*)Gcat + (size_t)b * Nn * OC + h * Dd + d0;
    short* dst = (short*)GrawT + (size_t)bh * 256 * YP + (size_t)d0 * YP;

    #pragma unroll
    for (int i = 0; i < 2; ++i) {
        const int task = i * 256 + tid;
        const int r = task >> 3, c8 = task & 7;
        const int y = y0 + r;
        bf16x8 v = {};
        if (y < Nn) v = *(const bf16x8*)(src + (size_t)y * OC + c8 * 8);
        *(bf16x8*)&Ls[r * 72 + c8 * 8] = v;
    }
    __syncthreads();
    #pragma unroll
    for (int i = 0; i < 2; ++i) {
        const int task = i * 256 + tid;
        const int dr = task >> 3, y8 = task & 7;
        const int yg = y0 + y8 * 8;
        if (yg < KAGG) {
            short tmp[8];
            #pragma unroll
            for (int j = 0; j < 8; ++j) tmp[j] = Ls[(y8 * 8 + j) * 72 + dr];
            *(bf16x8*)(dst + (size_t)dr * YP + yg) = *(bf16x8*)tmp;
        }
    }
}

// ---------------------------------------------------------------------------
// edge_fused: per (b,h) block. S = Gq.Gk^T via MFMA (full 131x131 in regs),
// sigmoid -> edge output; rowsum(adj*edge) -> dinv; write folded weight
// matrix Wb[x][y] = dinv_x*(adj*edge + I)*dinv_y*att_y (bf16, y-pad zeros).
// Waves 2x2, each 5x5 frags (80x80). LDS slabs 160x64 per k-chunk.
// ---------------------------------------------------------------------------
__global__ __launch_bounds__(256) void edge_fused(
    const __hip_bfloat16* __restrict__ Gcat, const float* __restrict__ adj,
    const float* __restrict__ att, float* __restrict__ edge,
    __hip_bfloat16* __restrict__ Wb)
{
    const int bh = blockIdx.x, b = bh >> 2, h = bh & 3;
    __shared__ short Qs[160 * 72];
    __shared__ short Ks[160 * 72];
    __shared__ float rs[XP];
    __shared__ float dinvL[XP];
    __shared__ float attL[Nn];
    const int tid = threadIdx.x;
    const int wave = tid >> 6, lane = tid & 63;
    const int wr = wave >> 1, wc = wave & 1;
    const int row0 = wr * 80, col0 = wc * 80;

    if (tid < Nn) attL[tid] = att[(size_t)b * Nn + tid];
    if (tid < XP) rs[tid] = 0.f;

    const short* qb = (const short*)Gcat + (size_t)b * Nn * OC + 2048 + h * Dd;
    const short* kb = (const short*)Gcat + (size_t)b * Nn * OC + 1024 + h * Dd;

    f32x4 acc[5][5] = {};

    for (int kc = 0; kc < 4; ++kc) {
        const int k0 = kc * 64;
        __syncthreads();            // previous chunk's reads complete
        // stage Q/K rows [0,131): 131 rows x 9 granules (72 shorts/row)
        #pragma unroll
        for (int i = 0; i < 5; ++i) {
            const int t = i * 256 + tid;
            if (t < 1179) {
                const int row = t / 9, part = t - row * 9;
                gload_lds16(qb + (size_t)row * OC + k0 + part * 8,
                            &Qs[(i * 256 + (tid & ~63)) * 8]);
                gload_lds16(kb + (size_t)row * OC + k0 + part * 8,
                            &Ks[(i * 256 + (tid & ~63)) * 8]);
            }
        }
        __syncthreads();            // staged data visible
        #pragma unroll
        for (int ks = 0; ks < 2; ++ks) {
            bf16x8 af[5], bfr[5];
            #pragma unroll
            for (int mi = 0; mi < 5; ++mi)
                af[mi] = *(const bf16x8*)&Qs[(row0 + mi * 16 + (lane & 15)) * 72 + ks * 32 + (lane >> 4) * 8];
            #pragma unroll
            for (int ni = 0; ni < 5; ++ni)
                bfr[ni] = *(const bf16x8*)&Ks[(col0 + ni * 16 + (lane & 15)) * 72 + ks * 32 + (lane >> 4) * 8];
            #pragma unroll
            for (int mi = 0; mi < 5; ++mi)
                #pragma unroll
                for (int ni = 0; ni < 5; ++ni)
                    acc[mi][ni] = __builtin_amdgcn_mfma_f32_16x16x32_bf16(
                        af[mi], bfr[ni], acc[mi][ni], 0, 0, 0);
        }
    }

    // pass 3: sigmoid, edge write, adj*edge row-sums
    const float* adjb = adj + (size_t)b * Nn * Nn;
    float* edgeb = edge + (size_t)bh * Nn * Nn;
    #pragma unroll
    for (int mi = 0; mi < 5; ++mi) {
        float rsum[4] = {0.f, 0.f, 0.f, 0.f};
        #pragma unroll
        for (int ni = 0; ni < 5; ++ni) {
            const int y = col0 + ni * 16 + (lane & 15);
            #pragma unroll
            for (int r = 0; r < 4; ++r) {
                const int x = row0 + mi * 16 + (lane >> 4) * 4 + r;
                const float e = 1.f / (1.f + __expf(-acc[mi][ni][r] * (1.f / 16.f)));
                acc[mi][ni][r] = e;
                if (x < Nn && y < Nn) {
                    edgeb[x * Nn + y] = e;
                    rsum[r] += adjb[x * Nn + y] * e;
                }
            }
        }
        #pragma unroll
        for (int r = 0; r < 4; ++r) {
            float v = rsum[r];
            v += __shfl_xor(v, 1); v += __shfl_xor(v, 2);
            v += __shfl_xor(v, 4); v += __shfl_xor(v, 8);
            const int x = row0 + mi * 16 + (lane >> 4) * 4 + r;
            if ((lane & 15) == 0 && x < Nn) atomicAdd(&rs[x], v);
        }
    }
    __syncthreads();
    if (tid < Nn) dinvL[tid] = rsqrtf(rs[tid] + 1.f);
    __syncthreads();

    // pass 4: folded weight matrix (bf16), y in [0,160) covered by frags
    __hip_bfloat16* wbb = Wb + (size_t)bh * XP * YP;
    #pragma unroll
    for (int mi = 0; mi < 5; ++mi)
        #pragma unroll
        for (int ni = 0; ni < 5; ++ni) {
            const int y = col0 + ni * 16 + (lane & 15);
            #pragma unroll
            for (int r = 0; r < 4; ++r) {
                const int x = row0 + mi * 16 + (lane >> 4) * 4 + r;
                if (x < Nn && y < KAGG) {
                    float w = 0.f;
                    if (y < Nn) {
                        float a = adjb[x * Nn + y] * acc[mi][ni][r];
                        if (x == y) a += 1.f;
                        w = dinvL[x] * a * dinvL[y] * attL[y];
                    }
                    wbb[(size_t)x * YP + y] = __float2bfloat16(w);
                }
            }
        }
}

// ---------------------------------------------------------------------------
// Aggregation MFMA: per (b,h), Gout[x][d] = sum_y Wb[x][y] * GrawT[d][y].
// 512 threads / 8 waves, each wave 32 d-cols; K=160 in 5 chunks of 32.
// ---------------------------------------------------------------------------
__global__ __launch_bounds__(512) void agg_mfma(
    const __hip_bfloat16* __restrict__ Wb, const __hip_bfloat16* __restrict__ GrawT,
    float* __restrict__ Gout)
{
    const int bh = blockIdx.x, b = bh >> 2, h = bh & 3;
    __shared__ short As[XP * 40];    // rows >=131 stale (discarded outputs)
    __shared__ short Bs[256 * 40];
    const int tid = threadIdx.x;
    const int wave = tid >> 6, lane = tid & 63;
    f32x4 acc[9][2] = {};
    const short* wsrc = (const short*)Wb + (size_t)bh * XP * YP;
    const short* gsrc = (const short*)GrawT + (size_t)bh * 256 * YP;

    for (int kc = 0; kc < 5; ++kc) {
        const int k0 = kc * 32;
        __syncthreads();
        #pragma unroll
        for (int i = 0; i < 2; ++i) {      // As: 131*5 = 655 granules
            const int t = i * 512 + tid;
            if (t < 655) {
                const int row = t / 5, part = t - row * 5;
                gload_lds16(wsrc + (size_t)row * YP + k0 + part * 8,
                            &As[(i * 512 + (tid & ~63)) * 8]);
            }
        }
        #pragma unroll
        for (int i = 0; i < 3; ++i) {      // Bs: 256*5 = 1280 granules
            const int t = i * 512 + tid;
            if (t < 1280) {
                const int row = t / 5, part = t - row * 5;
                gload_lds16(gsrc + (size_t)row * YP + k0 + part * 8,
                            &Bs[(i * 512 + (tid & ~63)) * 8]);
            }
        }
        __syncthreads();
        bf16x8 af[9], bfr[2];
        #pragma unroll
        for (int mi = 0; mi < 9; ++mi)
            af[mi] = *(const bf16x8*)&As[(mi * 16 + (lane & 15)) * 40 + (lane >> 4) * 8];
        #pragma unroll
        for (int ni = 0; ni < 2; ++ni)
            bfr[ni] = *(const bf16x8*)&Bs[(wave * 32 + ni * 16 + (lane & 15)) * 40 + (lane >> 4) * 8];
        #pragma unroll
        for (int mi = 0; mi < 9; ++mi)
            #pragma unroll
            for (int ni = 0; ni < 2; ++ni)
                acc[mi][ni] = __builtin_amdgcn_mfma_f32_16x16x32_bf16(
                    af[mi], bfr[ni], acc[mi][ni], 0, 0, 0);
    }

    float* gob = Gout + (size_t)b * Nn * OUTF + h * Dd;
    #pragma unroll
    for (int mi = 0; mi < 9; ++mi)
        #pragma unroll
        for (int ni = 0; ni < 2; ++ni) {
            const int d = wave * 32 + ni * 16 + (lane & 15);
            #pragma unroll
            for (int r = 0; r < 4; ++r) {
                const int x = mi * 16 + (lane >> 4) * 4 + r;
                if (x < Nn) gob[(size_t)x * OUTF + d] = acc[mi][ni][r];
            }
        }
}

// ---------------------------------------------------------------------------
// global_node[b,o] = lrelu(b_gs + sum_n W_gs[n]*Gout[b,n,o]); build Z_in.
// ---------------------------------------------------------------------------
__global__ __launch_bounds__(256) void gn_kernel(
    const float* __restrict__ Gout, const float* __restrict__ Wgs,
    const float* __restrict__ bgs, const float* __restrict__ Tx,
    float* __restrict__ Zin)
{
    __shared__ float wgs[Nn];
    if (threadIdx.x < Nn) wgs[threadIdx.x] = Wgs[threadIdx.x];
    __syncthreads();
    const int idx = blockIdx.x * 256 + threadIdx.x;
    const int b = idx >> 10, o = idx & 1023;
    float s = bgs[0];
    const float* g = Gout + (size_t)b * Nn * OUTF + o;
    for (int n = 0; n < Nn; ++n) s += wgs[n] * g[(size_t)n * OUTF];
    Zin[(size_t)b * 2048 + o] = LRELU(s);
    Zin[(size_t)b * 2048 + 1024 + o] = Tx[(size_t)b * OUTF + o];
}

// ---------------------------------------------------------------------------
extern "C" void kernel_launch(void* const* d_in, const int* in_sizes, int n_in,
                              void* d_out, int out_size, void* d_ws, size_t ws_size,
                              hipStream_t stream) {
    const float* tab  = (const float*)d_in[0];
    const float* node = (const float*)d_in[1];
    const float* adj  = (const float*)d_in[2];
    const float* W_gx = (const float*)d_in[3];
    const float* b_gx = (const float*)d_in[4];
    const float* W_tx = (const float*)d_in[5];
    const float* b_tx = (const float*)d_in[6];
    const float* W_gk = (const float*)d_in[7];
    const float* W_tq = (const float*)d_in[8];
    const float* W_gq = (const float*)d_in[9];
    const float* W_gs = (const float*)d_in[10];
    const float* b_gs = (const float*)d_in[11];
    const float* W_zx = (const float*)d_in[12];
    const float* b_zx = (const float*)d_in[13];

    const size_t GX_ELEMS = (size_t)Bb * Nn * OUTF;   // 34,340,864
    const int M_NODE = Bb * Nn;                       // 33536

    float* out   = (float*)d_out;
    float* o_GX  = out;
    float* o_TX  = o_GX + GX_ELEMS;
    float* o_ZX  = o_TX + (size_t)Bb * OUTF;
    float* o_ATT = o_ZX + (size_t)Bb * OUTF;
    float* o_EDG = o_ATT + (size_t)Bb * Nn;

    // workspace: bf16 regions first, then fp32
    __hip_bfloat16* wb      = (__hip_bfloat16*)d_ws;
    __hip_bfloat16* w_nodeb = wb;                                          // 33536*512
    __hip_bfloat16* w_Wcat  = w_nodeb + (size_t)M_NODE * INF_;             // 3072*512
    __hip_bfloat16* w_Gcat  = w_Wcat + (size_t)OC * INF_;                  // 33536*3072
    __hip_bfloat16* w_GrawT = w_Gcat + (size_t)M_NODE * OC;                // 1024*256*168
    __hip_bfloat16* w_Wb    = w_GrawT + (size_t)Bb * Hh * 256 * YP;        // 1024*144*168
    float* wf     = (float*)(w_Wb + (size_t)Bb * Hh * XP * YP);
    float* w_Tq   = wf;
    float* w_Zin  = w_Tq + (size_t)Bb * OUTF;

    const dim3 blk(256);

    // 0. fp32 -> bf16
    convert_kernel<<<dim3(2048), blk, 0, stream>>>(node, W_gx, W_gk, W_gq,
                                                   w_nodeb, w_Wcat);
    // 1. tabular GEMMs
    gemm_aw<<<dim3(16, 4), blk, 0, stream>>>(tab, W_tx, b_tx, o_TX, Bb, INF_, OUTF);
    gemm_aw<<<dim3(16, 4), blk, 0, stream>>>(tab, W_tq, nullptr, w_Tq, Bb, INF_, OUTF);
    // 2. fused node GEMM -> Gcat bf16 [33536][3072]
    gemm_node_mfma<<<dim3(OC / 128, M_NODE / 128), blk, 0, stream>>>(
        w_nodeb, w_Wcat, b_gx, w_Gcat);
    // 3. node attention -> o_ATT (softmax + 1)
    nodeatt_kernel<<<dim3(Bb), blk, 0, stream>>>(w_Tq, w_Gcat, o_ATT);
    // 4. transpose Graw head-slices -> GrawT
    transpose_kernel<<<dim3(4, 3, Bb * Hh), blk, 0, stream>>>(w_Gcat, w_GrawT);
    // 5. fused edge attention + degree norm + weight build
    edge_fused<<<dim3(Bb * Hh), blk, 0, stream>>>(w_Gcat, adj, o_ATT, o_EDG, w_Wb);
    // 6. aggregation MFMA -> o_GX
    agg_mfma<<<dim3(Bb * Hh), dim3(512), 0, stream>>>(w_Wb, w_GrawT, o_GX);
    // 7. graph summary + Z_in build
    gn_kernel<<<dim3((Bb * OUTF) / 256), blk, 0, stream>>>(o_GX, W_gs, b_gs, o_TX, w_Zin);
    // 8. final Z GEMM
    gemm_aw<<<dim3(16, 4), blk, 0, stream>>>(w_Zin, W_zx, b_zx, o_ZX, Bb, 2 * OUTF, OUTF);
}

// Round 4
// 750.052 us; speedup vs baseline: 3.8073x; 1.1425x over previous
//
#include <hip/hip_runtime.h>
#include <hip/hip_bf16.h>
#include <math.h>

// Dynamic_MHGCN_FusionLayer: B=256, N=131, IN=512, OUT=1024, H=4, D=256
// Round 4: de-fuse the latency-bound edge_fused monolith into three
// highly-parallel kernels (edge MFMA tiles + slotted rowsums, dinv combine,
// streaming Wb build). Deterministic (no float atomics).

#define LRELU(x) ((x) > 0.f ? (x) : 0.01f * (x))

constexpr int Bb = 256;
constexpr int Nn = 131;
constexpr int INF_ = 512;
constexpr int OUTF = 1024;
constexpr int Hh = 4;
constexpr int Dd = 256;
constexpr int OC = 3072;   // Graw(0..1023) | Gk(1024..2047) | Gq(2048..3071)
constexpr int YP = 168;    // padded y-stride (shorts) for Wb / GrawT rows
constexpr int KAGG = 160;  // padded K (y) for aggregation GEMM
constexpr int XP = 144;    // padded x rows for Wb

typedef __attribute__((ext_vector_type(8))) short bf16x8;
typedef __attribute__((ext_vector_type(4))) float f32x4;

__device__ __forceinline__ float bf2f(short s) {
    union { float f; unsigned u; } c;
    c.u = ((unsigned)(unsigned short)s) << 16;
    return c.f;
}

__device__ __forceinline__ void gload_lds16(const void* g, void* lds) {
    __builtin_amdgcn_global_load_lds(
        (const __attribute__((address_space(1))) void*)g,
        (__attribute__((address_space(3))) void*)lds, 16, 0, 0);
}

// ---------------------------------------------------------------------------
// fp32 -> bf16 conversion: node_feats and the packed weight matrix Wcat.
// ---------------------------------------------------------------------------
__global__ __launch_bounds__(256) void convert_kernel(
    const float* __restrict__ node, const float* __restrict__ Wgx,
    const float* __restrict__ Wgk, const float* __restrict__ Wgq,
    __hip_bfloat16* __restrict__ node_bf, __hip_bfloat16* __restrict__ Wcat)
{
    const size_t NE = (size_t)Bb * Nn * INF_ / 4;
    const size_t WE = (size_t)OC * INF_ / 4;
    for (size_t i = (size_t)blockIdx.x * 256 + threadIdx.x; i < NE + WE;
         i += (size_t)gridDim.x * 256) {
        if (i < NE) {
            const float4 v = ((const float4*)node)[i];
            __hip_bfloat16* o = node_bf + i * 4;
            o[0] = __float2bfloat16(v.x); o[1] = __float2bfloat16(v.y);
            o[2] = __float2bfloat16(v.z); o[3] = __float2bfloat16(v.w);
        } else {
            const size_t j = i - NE;
            const size_t which = j / (1024 * INF_ / 4);
            const float* src = (which == 0) ? Wgx : (which == 1 ? Wgk : Wgq);
            const size_t srcj = j - which * (1024 * INF_ / 4);
            const float4 v = ((const float4*)src)[srcj];
            __hip_bfloat16* o = Wcat + j * 4;
            o[0] = __float2bfloat16(v.x); o[1] = __float2bfloat16(v.y);
            o[2] = __float2bfloat16(v.z); o[3] = __float2bfloat16(v.w);
        }
    }
}

// ---------------------------------------------------------------------------
// Fused node GEMM (bf16 MFMA): Gcat[m][o] = lrelu(A[m][:] . Wcat[o][:] + bias)
// ---------------------------------------------------------------------------
__global__ __launch_bounds__(256) void gemm_node_mfma(
    const __hip_bfloat16* __restrict__ A, const __hip_bfloat16* __restrict__ W,
    const float* __restrict__ bias_gx, __hip_bfloat16* __restrict__ Gcat)
{
    __shared__ short As[128 * 32];
    __shared__ short Bs[128 * 32];
    const int tid = threadIdx.x;
    const int wave = tid >> 6, lane = tid & 63;
    const int m0 = blockIdx.y * 128, o0 = blockIdx.x * 128;
    const int wr = wave >> 1, wc = wave & 1;

    f32x4 acc[4][4] = {};
    const short* Asrc = (const short*)A;
    const short* Wsrc = (const short*)W;
    const int lr = lane >> 2;
    const int lcs = (lane & 3) * 8;

    for (int k0 = 0; k0 < INF_; k0 += 32) {
        #pragma unroll
        for (int t = 0; t < 2; ++t) {
            const int c = wave * 2 + t;
            gload_lds16(Asrc + (size_t)(m0 + c * 16 + lr) * INF_ + k0 + lcs,
                        &As[c * 512]);
            gload_lds16(Wsrc + (size_t)(o0 + c * 16 + lr) * INF_ + k0 + lcs,
                        &Bs[c * 512]);
        }
        __syncthreads();
        bf16x8 af[4], bfr[4];
        #pragma unroll
        for (int i = 0; i < 4; ++i) {
            af[i]  = *(const bf16x8*)&As[(wr * 64 + i * 16 + (lane & 15)) * 32 + (lane >> 4) * 8];
            bfr[i] = *(const bf16x8*)&Bs[(wc * 64 + i * 16 + (lane & 15)) * 32 + (lane >> 4) * 8];
        }
        #pragma unroll
        for (int mi = 0; mi < 4; ++mi)
            #pragma unroll
            for (int ni = 0; ni < 4; ++ni)
                acc[mi][ni] = __builtin_amdgcn_mfma_f32_16x16x32_bf16(
                    af[mi], bfr[ni], acc[mi][ni], 0, 0, 0);
        __syncthreads();
    }

    const int cc = lane & 15;
    const int rg = (lane >> 4) * 4;
    #pragma unroll
    for (int mi = 0; mi < 4; ++mi) {
        #pragma unroll
        for (int ni = 0; ni < 4; ++ni) {
            const int o = o0 + wc * 64 + ni * 16 + cc;
            const float badd = (o < OUTF) ? bias_gx[o] : 0.f;
            #pragma unroll
            for (int r = 0; r < 4; ++r) {
                const int m = m0 + wr * 64 + mi * 16 + rg + r;
                float v = acc[mi][ni][r] + badd;
                v = LRELU(v);
                Gcat[(size_t)m * OC + o] = __float2bfloat16(v);
            }
        }
    }
}

// ---------------------------------------------------------------------------
// Generic fp32 tiled GEMM (small tabular / Z GEMMs).
// ---------------------------------------------------------------------------
__global__ __launch_bounds__(256) void gemm_aw(
    const float* __restrict__ A, const float* __restrict__ W,
    const float* __restrict__ bias, float* __restrict__ C,
    int M, int K, int O)
{
    __shared__ float As[16][68];
    __shared__ float Ws[16][68];
    const int tid = threadIdx.x;
    const int tx = tid & 15;
    const int ty = tid >> 4;
    const int m0 = blockIdx.y * 64;
    const int o0 = blockIdx.x * 64;

    float acc[4][4] = {};

    for (int k0 = 0; k0 < K; k0 += 16) {
        const int j = tid & 15;
        const int i = tid >> 4;
        #pragma unroll
        for (int r = 0; r < 4; ++r)
            As[j][i + 16 * r] = A[(size_t)(m0 + i + 16 * r) * K + k0 + j];
        #pragma unroll
        for (int r = 0; r < 4; ++r)
            Ws[j][i + 16 * r] = W[(size_t)(o0 + i + 16 * r) * K + k0 + j];
        __syncthreads();
        #pragma unroll
        for (int kk = 0; kk < 16; ++kk) {
            const float4 av = *(const float4*)&As[kk][ty * 4];
            const float4 wv = *(const float4*)&Ws[kk][tx * 4];
            const float a[4] = {av.x, av.y, av.z, av.w};
            const float w[4] = {wv.x, wv.y, wv.z, wv.w};
            #pragma unroll
            for (int r = 0; r < 4; ++r)
                #pragma unroll
                for (int c = 0; c < 4; ++c)
                    acc[r][c] += a[r] * w[c];
        }
        __syncthreads();
    }

    #pragma unroll
    for (int r = 0; r < 4; ++r) {
        const int m = m0 + ty * 4 + r;
        const int o = o0 + tx * 4;
        float4 v;
        float* vp = (float*)&v;
        #pragma unroll
        for (int c = 0; c < 4; ++c) {
            float t = acc[r][c] + (bias ? bias[o + c] : 0.f);
            vp[c] = LRELU(t);
        }
        *(float4*)&C[(size_t)m * O + o] = v;
    }
}

// ---------------------------------------------------------------------------
// node_att softmax: s[b,n] = (1/32) * Tq[b,:] . Gk[b,n,:]; softmax over n; +1.
// ---------------------------------------------------------------------------
__global__ __launch_bounds__(256) void nodeatt_kernel(
    const float* __restrict__ Tq, const __hip_bfloat16* __restrict__ Gcat,
    float* __restrict__ att)
{
    const int b = blockIdx.x;
    __shared__ float tq[OUTF];
    __shared__ float sc[136];
    const int tid = threadIdx.x;
    for (int o = tid; o < OUTF; o += 256) tq[o] = Tq[(size_t)b * OUTF + o];
    __syncthreads();

    const int wave = tid >> 6, lane = tid & 63;
    for (int n = wave; n < Nn; n += 4) {
        const short4* gk = (const short4*)((const short*)Gcat + ((size_t)b * Nn + n) * OC + 1024);
        float s = 0.f;
        for (int o4 = lane; o4 < 256; o4 += 64) {
            const short4 v = gk[o4];
            s += tq[o4 * 4 + 0] * bf2f(v.x) + tq[o4 * 4 + 1] * bf2f(v.y)
               + tq[o4 * 4 + 2] * bf2f(v.z) + tq[o4 * 4 + 3] * bf2f(v.w);
        }
        #pragma unroll
        for (int off = 32; off; off >>= 1) s += __shfl_xor(s, off);
        if (lane == 0) sc[n] = s * (1.f / 32.f);
    }
    __syncthreads();

    if (tid < 64) {
        const float v1 = sc[tid];
        const float v2 = sc[tid + 64];
        const float v3 = (tid < 3) ? sc[tid + 128] : -1e30f;
        float m = fmaxf(fmaxf(v1, v2), v3);
        #pragma unroll
        for (int off = 32; off; off >>= 1) m = fmaxf(m, __shfl_xor(m, off));
        const float e1 = expf(v1 - m);
        const float e2 = expf(v2 - m);
        const float e3 = (tid < 3) ? expf(v3 - m) : 0.f;
        float s = e1 + e2 + e3;
        #pragma unroll
        for (int off = 32; off; off >>= 1) s += __shfl_xor(s, off);
        const float inv = 1.f / s;
        float* ab = att + (size_t)b * Nn;
        ab[tid] = e1 * inv + 1.f;
        ab[tid + 64] = e2 * inv + 1.f;
        if (tid < 3) ab[tid + 128] = e3 * inv + 1.f;
    }
}

// ---------------------------------------------------------------------------
// Transpose Graw head-slices: GrawT[bh][d][y] (y padded to 160 with zeros,
// stride YP). 64x64 LDS tiles, grid (4 d-tiles, 3 y-tiles, B*H).
// ---------------------------------------------------------------------------
__global__ __launch_bounds__(256) void transpose_kernel(
    const __hip_bfloat16* __restrict__ Gcat, __hip_bfloat16* __restrict__ GrawT)
{
    const int bh = blockIdx.z, b = bh >> 2, h = bh & 3;
    const int d0 = blockIdx.x * 64, y0 = blockIdx.y * 64;
    __shared__ short Ls[64 * 72];
    const int tid = threadIdx.x;
    const short* src = (const short*)Gcat + (size_t)b * Nn * OC + h * Dd + d0;
    short* dst = (short*)GrawT + (size_t)bh * 256 * YP + (size_t)d0 * YP;

    #pragma unroll
    for (int i = 0; i < 2; ++i) {
        const int task = i * 256 + tid;
        const int r = task >> 3, c8 = task & 7;
        const int y = y0 + r;
        bf16x8 v = {};
        if (y < Nn) v = *(const bf16x8*)(src + (size_t)y * OC + c8 * 8);
        *(bf16x8*)&Ls[r * 72 + c8 * 8] = v;
    }
    __syncthreads();
    #pragma unroll
    for (int i = 0; i < 2; ++i) {
        const int task = i * 256 + tid;
        const int dr = task >> 3, y8 = task & 7;
        const int yg = y0 + y8 * 8;
        if (yg < KAGG) {
            short tmp[8];
            #pragma unroll
            for (int j = 0; j < 8; ++j) tmp[j] = Ls[(y8 * 8 + j) * 72 + dr];
            *(bf16x8*)(dst + (size_t)dr * YP + yg) = *(bf16x8*)tmp;
        }
    }
}

// ---------------------------------------------------------------------------
// edge_mfma_rs: 64x64 tile edge attention + sigmoid + edge write + slotted
// partial rowsums of adj*edge. Grid (3 ytiles, 3 xtiles, B*H).
// rs[slot][bh][x], slot = ytile*2 + wave_col (6 slots, no atomics).
// ---------------------------------------------------------------------------
__global__ __launch_bounds__(256) void edge_mfma_rs(
    const __hip_bfloat16* __restrict__ Gcat, const float* __restrict__ adj,
    float* __restrict__ edge, float* __restrict__ rs)
{
    const int bh = blockIdx.z;
    const int b = bh >> 2, h = bh & 3;
    const int x0 = blockIdx.y * 64, y0 = blockIdx.x * 64;
    __shared__ short Qs[64 * 32];
    __shared__ short Ks[64 * 32];
    const int tid = threadIdx.x;
    const int wave = tid >> 6, lane = tid & 63;
    const int wr = wave >> 1, wc = wave & 1;
    f32x4 acc[2][2] = {};
    const short* qbase = (const short*)Gcat + (size_t)b * Nn * OC + 2048 + h * Dd;
    const short* kbase = (const short*)Gcat + (size_t)b * Nn * OC + 1024 + h * Dd;
    const int lr = lane >> 2, lcs = (lane & 3) * 8;

    for (int k0 = 0; k0 < Dd; k0 += 32) {
        {
            const int c = wave;
            int xr = x0 + c * 16 + lr; if (xr > Nn - 1) xr = Nn - 1;
            gload_lds16(qbase + (size_t)xr * OC + k0 + lcs, &Qs[c * 512]);
            int yr = y0 + c * 16 + lr; if (yr > Nn - 1) yr = Nn - 1;
            gload_lds16(kbase + (size_t)yr * OC + k0 + lcs, &Ks[c * 512]);
        }
        __syncthreads();
        bf16x8 qf[2], kf[2];
        #pragma unroll
        for (int i = 0; i < 2; ++i) {
            qf[i] = *(const bf16x8*)&Qs[(wr * 32 + i * 16 + (lane & 15)) * 32 + (lane >> 4) * 8];
            kf[i] = *(const bf16x8*)&Ks[(wc * 32 + i * 16 + (lane & 15)) * 32 + (lane >> 4) * 8];
        }
        #pragma unroll
        for (int mi = 0; mi < 2; ++mi)
            #pragma unroll
            for (int ni = 0; ni < 2; ++ni)
                acc[mi][ni] = __builtin_amdgcn_mfma_f32_16x16x32_bf16(
                    qf[mi], kf[ni], acc[mi][ni], 0, 0, 0);
        __syncthreads();
    }

    const int cc = lane & 15;
    const int rg = (lane >> 4) * 4;
    const float* adjb = adj + (size_t)b * Nn * Nn;
    float* edgeb = edge + (size_t)bh * Nn * Nn;
    float* rsb = rs + ((size_t)(blockIdx.x * 2 + wc) * (Bb * Hh) + bh) * Nn;
    #pragma unroll
    for (int mi = 0; mi < 2; ++mi) {
        float rsum[4] = {0.f, 0.f, 0.f, 0.f};
        #pragma unroll
        for (int ni = 0; ni < 2; ++ni) {
            const int y = y0 + wc * 32 + ni * 16 + cc;
            #pragma unroll
            for (int r = 0; r < 4; ++r) {
                const int x = x0 + wr * 32 + mi * 16 + rg + r;
                const float e = 1.f / (1.f + __expf(-acc[mi][ni][r] * (1.f / 16.f)));
                if (x < Nn && y < Nn) {
                    edgeb[x * Nn + y] = e;
                    rsum[r] += adjb[x * Nn + y] * e;
                }
            }
        }
        #pragma unroll
        for (int r = 0; r < 4; ++r) {
            float v = rsum[r];
            v += __shfl_xor(v, 1); v += __shfl_xor(v, 2);
            v += __shfl_xor(v, 4); v += __shfl_xor(v, 8);
            const int x = x0 + wr * 32 + mi * 16 + rg + r;
            if (cc == 0 && x < Nn) rsb[x] = v;
        }
    }
}

// ---------------------------------------------------------------------------
// dinv combine: dinvx[bh,n] = rsqrt(1 + sum_slots rs), dinvatt = dinvx*att.
// ---------------------------------------------------------------------------
__global__ __launch_bounds__(256) void dinv_kernel(
    const float* __restrict__ rs, const float* __restrict__ att,
    float* __restrict__ dinvx, float* __restrict__ dinvatt)
{
    const int i = blockIdx.x * 256 + threadIdx.x;
    if (i >= Bb * Hh * Nn) return;
    const int n = i % Nn;
    const int bh = i / Nn;
    const int b = bh >> 2;
    float s = 0.f;
    #pragma unroll
    for (int sl = 0; sl < 6; ++sl) s += rs[(size_t)sl * (Bb * Hh * Nn) + i];
    const float dv = rsqrtf(s + 1.f);
    dinvx[i] = dv;
    dinvatt[i] = dv * att[(size_t)b * Nn + n];
}

// ---------------------------------------------------------------------------
// Wb build (streaming): Wb[bh][x][y] = dinvx*(adj*edge + I)*dinvatt_y, bf16,
// y-padded to 160 with zeros. One 8-element granule per thread.
// ---------------------------------------------------------------------------
__global__ __launch_bounds__(256) void wbuild_kernel(
    const float* __restrict__ adj, const float* __restrict__ edge,
    const float* __restrict__ dinvx, const float* __restrict__ dinvatt,
    __hip_bfloat16* __restrict__ Wb)
{
    const int t = blockIdx.x * 256 + threadIdx.x;
    const int g = t % 20;
    const int rem = t / 20;
    const int x = rem % Nn;
    const int bh = rem / Nn;
    const int b = bh >> 2;
    const float dx = dinvx[(size_t)bh * Nn + x];
    const float* er = edge + ((size_t)bh * Nn + x) * Nn;
    const float* ar = adj + ((size_t)b * Nn + x) * Nn;
    const float* da = dinvatt + (size_t)bh * Nn;
    short outv[8];
    #pragma unroll
    for (int j = 0; j < 8; ++j) {
        const int y = g * 8 + j;
        float w = 0.f;
        if (y < Nn) {
            float a = ar[y] * er[y];
            if (x == y) a += 1.f;
            w = dx * a * da[y];
        }
        __hip_bfloat16 hb = __float2bfloat16(w);
        outv[j] = *(short*)&hb;
    }
    *(bf16x8*)((short*)Wb + (size_t)bh * XP * YP + (size_t)x * YP + g * 8) =
        *(bf16x8*)outv;
}

// ---------------------------------------------------------------------------
// Aggregation MFMA: per (b,h), Gout[x][d] = sum_y Wb[x][y] * GrawT[d][y].
// ---------------------------------------------------------------------------
__global__ __launch_bounds__(512) void agg_mfma(
    const __hip_bfloat16* __restrict__ Wb, const __hip_bfloat16* __restrict__ GrawT,
    float* __restrict__ Gout)
{
    const int bh = blockIdx.x, b = bh >> 2, h = bh & 3;
    __shared__ short As[XP * 40];
    __shared__ short Bs[256 * 40];
    const int tid = threadIdx.x;
    const int wave = tid >> 6, lane = tid & 63;
    f32x4 acc[9][2] = {};
    const short* wsrc = (const short*)Wb + (size_t)bh * XP * YP;
    const short* gsrc = (const short*)GrawT + (size_t)bh * 256 * YP;

    for (int kc = 0; kc < 5; ++kc) {
        const int k0 = kc * 32;
        __syncthreads();
        #pragma unroll
        for (int i = 0; i < 2; ++i) {
            const int t = i * 512 + tid;
            if (t < 655) {
                const int row = t / 5, part = t - row * 5;
                gload_lds16(wsrc + (size_t)row * YP + k0 + part * 8,
                            &As[(i * 512 + (tid & ~63)) * 8]);
            }
        }
        #pragma unroll
        for (int i = 0; i < 3; ++i) {
            const int t = i * 512 + tid;
            if (t < 1280) {
                const int row = t / 5, part = t - row * 5;
                gload_lds16(gsrc + (size_t)row * YP + k0 + part * 8,
                            &Bs[(i * 512 + (tid & ~63)) * 8]);
            }
        }
        __syncthreads();
        bf16x8 af[9], bfr[2];
        #pragma unroll
        for (int mi = 0; mi < 9; ++mi)
            af[mi] = *(const bf16x8*)&As[(mi * 16 + (lane & 15)) * 40 + (lane >> 4) * 8];
        #pragma unroll
        for (int ni = 0; ni < 2; ++ni)
            bfr[ni] = *(const bf16x8*)&Bs[(wave * 32 + ni * 16 + (lane & 15)) * 40 + (lane >> 4) * 8];
        #pragma unroll
        for (int mi = 0; mi < 9; ++mi)
            #pragma unroll
            for (int ni = 0; ni < 2; ++ni)
                acc[mi][ni] = __builtin_amdgcn_mfma_f32_16x16x32_bf16(
                    af[mi], bfr[ni], acc[mi][ni], 0, 0, 0);
    }

    float* gob = Gout + (size_t)b * Nn * OUTF + h * Dd;
    #pragma unroll
    for (int mi = 0; mi < 9; ++mi)
        #pragma unroll
        for (int ni = 0; ni < 2; ++ni) {
            const int d = wave * 32 + ni * 16 + (lane & 15);
            #pragma unroll
            for (int r = 0; r < 4; ++r) {
                const int x = mi * 16 + (lane >> 4) * 4 + r;
                if (x < Nn) gob[(size_t)x * OUTF + d] = acc[mi][ni][r];
            }
        }
}

// ---------------------------------------------------------------------------
// global_node[b,o] = lrelu(b_gs + sum_n W_gs[n]*Gout[b,n,o]); build Z_in.
// ---------------------------------------------------------------------------
__global__ __launch_bounds__(256) void gn_kernel(
    const float* __restrict__ Gout, const float* __restrict__ Wgs,
    const float* __restrict__ bgs, const float* __restrict__ Tx,
    float* __restrict__ Zin)
{
    __shared__ float wgs[Nn];
    if (threadIdx.x < Nn) wgs[threadIdx.x] = Wgs[threadIdx.x];
    __syncthreads();
    const int idx = blockIdx.x * 256 + threadIdx.x;
    const int b = idx >> 10, o = idx & 1023;
    float s = bgs[0];
    const float* g = Gout + (size_t)b * Nn * OUTF + o;
    for (int n = 0; n < Nn; ++n) s += wgs[n] * g[(size_t)n * OUTF];
    Zin[(size_t)b * 2048 + o] = LRELU(s);
    Zin[(size_t)b * 2048 + 1024 + o] = Tx[(size_t)b * OUTF + o];
}

// ---------------------------------------------------------------------------
extern "C" void kernel_launch(void* const* d_in, const int* in_sizes, int n_in,
                              void* d_out, int out_size, void* d_ws, size_t ws_size,
                              hipStream_t stream) {
    const float* tab  = (const float*)d_in[0];
    const float* node = (const float*)d_in[1];
    const float* adj  = (const float*)d_in[2];
    const float* W_gx = (const float*)d_in[3];
    const float* b_gx = (const float*)d_in[4];
    const float* W_tx = (const float*)d_in[5];
    const float* b_tx = (const float*)d_in[6];
    const float* W_gk = (const float*)d_in[7];
    const float* W_tq = (const float*)d_in[8];
    const float* W_gq = (const float*)d_in[9];
    const float* W_gs = (const float*)d_in[10];
    const float* b_gs = (const float*)d_in[11];
    const float* W_zx = (const float*)d_in[12];
    const float* b_zx = (const float*)d_in[13];

    const size_t GX_ELEMS = (size_t)Bb * Nn * OUTF;   // 34,340,864
    const int M_NODE = Bb * Nn;                       // 33536

    float* out   = (float*)d_out;
    float* o_GX  = out;
    float* o_TX  = o_GX + GX_ELEMS;
    float* o_ZX  = o_TX + (size_t)Bb * OUTF;
    float* o_ATT = o_ZX + (size_t)Bb * OUTF;
    float* o_EDG = o_ATT + (size_t)Bb * Nn;

    // workspace: bf16 regions first, then fp32
    __hip_bfloat16* wb      = (__hip_bfloat16*)d_ws;
    __hip_bfloat16* w_nodeb = wb;                                          // 33536*512
    __hip_bfloat16* w_Wcat  = w_nodeb + (size_t)M_NODE * INF_;             // 3072*512
    __hip_bfloat16* w_Gcat  = w_Wcat + (size_t)OC * INF_;                  // 33536*3072
    __hip_bfloat16* w_GrawT = w_Gcat + (size_t)M_NODE * OC;                // 1024*256*168
    __hip_bfloat16* w_Wb    = w_GrawT + (size_t)Bb * Hh * 256 * YP;        // 1024*144*168
    float* wf       = (float*)(w_Wb + (size_t)Bb * Hh * XP * YP);
    float* w_Tq     = wf;
    float* w_Zin    = w_Tq + (size_t)Bb * OUTF;
    float* w_rs     = w_Zin + (size_t)Bb * 2 * OUTF;                       // 6*1024*131
    float* w_dinvx  = w_rs + (size_t)6 * Bb * Hh * Nn;
    float* w_dinvat = w_dinvx + (size_t)Bb * Hh * Nn;

    const dim3 blk(256);

    // 0. fp32 -> bf16
    convert_kernel<<<dim3(2048), blk, 0, stream>>>(node, W_gx, W_gk, W_gq,
                                                   w_nodeb, w_Wcat);
    // 1. tabular GEMMs
    gemm_aw<<<dim3(16, 4), blk, 0, stream>>>(tab, W_tx, b_tx, o_TX, Bb, INF_, OUTF);
    gemm_aw<<<dim3(16, 4), blk, 0, stream>>>(tab, W_tq, nullptr, w_Tq, Bb, INF_, OUTF);
    // 2. fused node GEMM -> Gcat bf16 [33536][3072]
    gemm_node_mfma<<<dim3(OC / 128, M_NODE / 128), blk, 0, stream>>>(
        w_nodeb, w_Wcat, b_gx, w_Gcat);
    // 3. node attention -> o_ATT (softmax + 1)
    nodeatt_kernel<<<dim3(Bb), blk, 0, stream>>>(w_Tq, w_Gcat, o_ATT);
    // 4. transpose Graw head-slices -> GrawT
    transpose_kernel<<<dim3(4, 3, Bb * Hh), blk, 0, stream>>>(w_Gcat, w_GrawT);
    // 5. edge attention + slotted rowsums
    edge_mfma_rs<<<dim3(3, 3, Bb * Hh), blk, 0, stream>>>(w_Gcat, adj, o_EDG, w_rs);
    // 6. dinv combine
    dinv_kernel<<<dim3((Bb * Hh * Nn + 255) / 256), blk, 0, stream>>>(
        w_rs, o_ATT, w_dinvx, w_dinvat);
    // 7. folded weight build -> Wb
    wbuild_kernel<<<dim3(Bb * Hh * Nn * 20 / 256), blk, 0, stream>>>(
        adj, o_EDG, w_dinvx, w_dinvat, w_Wb);
    // 8. aggregation MFMA -> o_GX
    agg_mfma<<<dim3(Bb * Hh), dim3(512), 0, stream>>>(w_Wb, w_GrawT, o_GX);
    // 9. graph summary + Z_in build
    gn_kernel<<<dim3((Bb * OUTF) / 256), blk, 0, stream>>>(o_GX, W_gs, b_gs, o_TX, w_Zin);
    // 10. final Z GEMM
    gemm_aw<<<dim3(16, 4), blk, 0, stream>>>(w_Zin, W_zx, b_zx, o_ZX, Bb, 2 * OUTF, OUTF);
}

// Round 5
// 728.544 us; speedup vs baseline: 3.9197x; 1.0295x over previous
//
#include <hip/hip_runtime.h>
#include <hip/hip_bf16.h>
#include <math.h>

// Dynamic_MHGCN_FusionLayer: B=256, N=131, IN=512, OUT=1024, H=4, D=256
// Round 5: double-buffered 2-phase K-loops with counted vmcnt + raw barriers
// (T3-minimum) + setprio (T5) + bijective XCD swizzle (T1) on the node GEMM;
// same dbuf on edge kernel; dinv merged into wbuild.

#define LRELU(x) ((x) > 0.f ? (x) : 0.01f * (x))

constexpr int Bb = 256;
constexpr int Nn = 131;
constexpr int INF_ = 512;
constexpr int OUTF = 1024;
constexpr int Hh = 4;
constexpr int Dd = 256;
constexpr int OC = 3072;   // Graw(0..1023) | Gk(1024..2047) | Gq(2048..3071)
constexpr int YP = 168;    // padded y-stride (shorts) for Wb / GrawT rows
constexpr int KAGG = 160;  // padded K (y) for aggregation GEMM
constexpr int XP = 144;    // padded x rows for Wb

typedef __attribute__((ext_vector_type(8))) short bf16x8;
typedef __attribute__((ext_vector_type(4))) float f32x4;

__device__ __forceinline__ float bf2f(short s) {
    union { float f; unsigned u; } c;
    c.u = ((unsigned)(unsigned short)s) << 16;
    return c.f;
}

__device__ __forceinline__ void gload_lds16(const void* g, void* lds) {
    __builtin_amdgcn_global_load_lds(
        (const __attribute__((address_space(1))) void*)g,
        (__attribute__((address_space(3))) void*)lds, 16, 0, 0);
}

// ---------------------------------------------------------------------------
// fp32 -> bf16 conversion: node_feats and the packed weight matrix Wcat.
// ---------------------------------------------------------------------------
__global__ __launch_bounds__(256) void convert_kernel(
    const float* __restrict__ node, const float* __restrict__ Wgx,
    const float* __restrict__ Wgk, const float* __restrict__ Wgq,
    __hip_bfloat16* __restrict__ node_bf, __hip_bfloat16* __restrict__ Wcat)
{
    const size_t NE = (size_t)Bb * Nn * INF_ / 4;
    const size_t WE = (size_t)OC * INF_ / 4;
    for (size_t i = (size_t)blockIdx.x * 256 + threadIdx.x; i < NE + WE;
         i += (size_t)gridDim.x * 256) {
        if (i < NE) {
            const float4 v = ((const float4*)node)[i];
            __hip_bfloat16* o = node_bf + i * 4;
            o[0] = __float2bfloat16(v.x); o[1] = __float2bfloat16(v.y);
            o[2] = __float2bfloat16(v.z); o[3] = __float2bfloat16(v.w);
        } else {
            const size_t j = i - NE;
            const size_t which = j / (1024 * INF_ / 4);
            const float* src = (which == 0) ? Wgx : (which == 1 ? Wgk : Wgq);
            const size_t srcj = j - which * (1024 * INF_ / 4);
            const float4 v = ((const float4*)src)[srcj];
            __hip_bfloat16* o = Wcat + j * 4;
            o[0] = __float2bfloat16(v.x); o[1] = __float2bfloat16(v.y);
            o[2] = __float2bfloat16(v.z); o[3] = __float2bfloat16(v.w);
        }
    }
}

// ---------------------------------------------------------------------------
// Fused node GEMM (bf16 MFMA), double-buffered 2-phase:
// Gcat[m][o] = lrelu(A[m][:] . Wcat[o][:] + bias). 128x128 tile, BK=32.
// 1D grid 6288 = 24 o-tiles x 262 m-tiles, XCD-swizzled (6288 % 8 == 0).
// Per wave per STAGE: 4 gload_lds -> counted s_waitcnt vmcnt(4).
// ---------------------------------------------------------------------------
__global__ __launch_bounds__(256) void gemm_node_mfma(
    const __hip_bfloat16* __restrict__ A, const __hip_bfloat16* __restrict__ W,
    const float* __restrict__ bias_gx, __hip_bfloat16* __restrict__ Gcat)
{
    __shared__ short As[2][128 * 32];
    __shared__ short Bs[2][128 * 32];
    const int tid = threadIdx.x;
    const int wave = tid >> 6, lane = tid & 63;
    // bijective XCD swizzle: nwg = 6288, 786 per XCD
    const int swz = (blockIdx.x & 7) * 786 + (blockIdx.x >> 3);
    const int o0 = (swz % 24) * 128;
    const int m0 = (swz / 24) * 128;
    const int wr = wave >> 1, wc = wave & 1;

    f32x4 acc[4][4] = {};
    const short* Asrc = (const short*)A;
    const short* Wsrc = (const short*)W;
    const int lr = lane >> 2;
    const int lcs = (lane & 3) * 8;

    // stage one K-chunk (128 rows x 32 k) of A and B into buffer `buf`
    auto STAGE = [&](int buf, int k0) {
        #pragma unroll
        for (int t = 0; t < 2; ++t) {
            const int c = wave * 2 + t;
            gload_lds16(Asrc + (size_t)(m0 + c * 16 + lr) * INF_ + k0 + lcs,
                        &As[buf][c * 512]);
            gload_lds16(Wsrc + (size_t)(o0 + c * 16 + lr) * INF_ + k0 + lcs,
                        &Bs[buf][c * 512]);
        }
    };

    STAGE(0, 0);                                   // 4 outstanding
    for (int t = 0; t < 16; ++t) {
        const int buf = t & 1;
        if (t < 15) {
            STAGE(buf ^ 1, (t + 1) * 32);          // +4 -> 8 outstanding
            asm volatile("s_waitcnt vmcnt(4)" ::: "memory");  // old 4 done
        } else {
            asm volatile("s_waitcnt vmcnt(0)" ::: "memory");
        }
        __builtin_amdgcn_s_barrier();              // buf ready for all waves
        __builtin_amdgcn_sched_barrier(0);
        bf16x8 af[4], bfr[4];
        #pragma unroll
        for (int i = 0; i < 4; ++i) {
            af[i]  = *(const bf16x8*)&As[buf][(wr * 64 + i * 16 + (lane & 15)) * 32 + (lane >> 4) * 8];
            bfr[i] = *(const bf16x8*)&Bs[buf][(wc * 64 + i * 16 + (lane & 15)) * 32 + (lane >> 4) * 8];
        }
        __builtin_amdgcn_s_setprio(1);
        #pragma unroll
        for (int mi = 0; mi < 4; ++mi)
            #pragma unroll
            for (int ni = 0; ni < 4; ++ni)
                acc[mi][ni] = __builtin_amdgcn_mfma_f32_16x16x32_bf16(
                    af[mi], bfr[ni], acc[mi][ni], 0, 0, 0);
        __builtin_amdgcn_s_setprio(0);
        __builtin_amdgcn_sched_barrier(0);
        if (t < 15) __builtin_amdgcn_s_barrier();  // reads done -> next overwrite ok
    }

    const int cc = lane & 15;
    const int rg = (lane >> 4) * 4;
    #pragma unroll
    for (int mi = 0; mi < 4; ++mi) {
        #pragma unroll
        for (int ni = 0; ni < 4; ++ni) {
            const int o = o0 + wc * 64 + ni * 16 + cc;
            const float badd = (o < OUTF) ? bias_gx[o] : 0.f;
            #pragma unroll
            for (int r = 0; r < 4; ++r) {
                const int m = m0 + wr * 64 + mi * 16 + rg + r;
                float v = acc[mi][ni][r] + badd;
                v = LRELU(v);
                Gcat[(size_t)m * OC + o] = __float2bfloat16(v);
            }
        }
    }
}

// ---------------------------------------------------------------------------
// Generic fp32 tiled GEMM (small tabular / Z GEMMs).
// ---------------------------------------------------------------------------
__global__ __launch_bounds__(256) void gemm_aw(
    const float* __restrict__ A, const float* __restrict__ W,
    const float* __restrict__ bias, float* __restrict__ C,
    int M, int K, int O)
{
    __shared__ float As[16][68];
    __shared__ float Ws[16][68];
    const int tid = threadIdx.x;
    const int tx = tid & 15;
    const int ty = tid >> 4;
    const int m0 = blockIdx.y * 64;
    const int o0 = blockIdx.x * 64;

    float acc[4][4] = {};

    for (int k0 = 0; k0 < K; k0 += 16) {
        const int j = tid & 15;
        const int i = tid >> 4;
        #pragma unroll
        for (int r = 0; r < 4; ++r)
            As[j][i + 16 * r] = A[(size_t)(m0 + i + 16 * r) * K + k0 + j];
        #pragma unroll
        for (int r = 0; r < 4; ++r)
            Ws[j][i + 16 * r] = W[(size_t)(o0 + i + 16 * r) * K + k0 + j];
        __syncthreads();
        #pragma unroll
        for (int kk = 0; kk < 16; ++kk) {
            const float4 av = *(const float4*)&As[kk][ty * 4];
            const float4 wv = *(const float4*)&Ws[kk][tx * 4];
            const float a[4] = {av.x, av.y, av.z, av.w};
            const float w[4] = {wv.x, wv.y, wv.z, wv.w};
            #pragma unroll
            for (int r = 0; r < 4; ++r)
                #pragma unroll
                for (int c = 0; c < 4; ++c)
                    acc[r][c] += a[r] * w[c];
        }
        __syncthreads();
    }

    #pragma unroll
    for (int r = 0; r < 4; ++r) {
        const int m = m0 + ty * 4 + r;
        const int o = o0 + tx * 4;
        float4 v;
        float* vp = (float*)&v;
        #pragma unroll
        for (int c = 0; c < 4; ++c) {
            float t = acc[r][c] + (bias ? bias[o + c] : 0.f);
            vp[c] = LRELU(t);
        }
        *(float4*)&C[(size_t)m * O + o] = v;
    }
}

// ---------------------------------------------------------------------------
// node_att softmax: s[b,n] = (1/32) * Tq[b,:] . Gk[b,n,:]; softmax over n; +1.
// ---------------------------------------------------------------------------
__global__ __launch_bounds__(256) void nodeatt_kernel(
    const float* __restrict__ Tq, const __hip_bfloat16* __restrict__ Gcat,
    float* __restrict__ att)
{
    const int b = blockIdx.x;
    __shared__ float tq[OUTF];
    __shared__ float sc[136];
    const int tid = threadIdx.x;
    for (int o = tid; o < OUTF; o += 256) tq[o] = Tq[(size_t)b * OUTF + o];
    __syncthreads();

    const int wave = tid >> 6, lane = tid & 63;
    for (int n = wave; n < Nn; n += 4) {
        const short4* gk = (const short4*)((const short*)Gcat + ((size_t)b * Nn + n) * OC + 1024);
        float s = 0.f;
        for (int o4 = lane; o4 < 256; o4 += 64) {
            const short4 v = gk[o4];
            s += tq[o4 * 4 + 0] * bf2f(v.x) + tq[o4 * 4 + 1] * bf2f(v.y)
               + tq[o4 * 4 + 2] * bf2f(v.z) + tq[o4 * 4 + 3] * bf2f(v.w);
        }
        #pragma unroll
        for (int off = 32; off; off >>= 1) s += __shfl_xor(s, off);
        if (lane == 0) sc[n] = s * (1.f / 32.f);
    }
    __syncthreads();

    if (tid < 64) {
        const float v1 = sc[tid];
        const float v2 = sc[tid + 64];
        const float v3 = (tid < 3) ? sc[tid + 128] : -1e30f;
        float m = fmaxf(fmaxf(v1, v2), v3);
        #pragma unroll
        for (int off = 32; off; off >>= 1) m = fmaxf(m, __shfl_xor(m, off));
        const float e1 = expf(v1 - m);
        const float e2 = expf(v2 - m);
        const float e3 = (tid < 3) ? expf(v3 - m) : 0.f;
        float s = e1 + e2 + e3;
        #pragma unroll
        for (int off = 32; off; off >>= 1) s += __shfl_xor(s, off);
        const float inv = 1.f / s;
        float* ab = att + (size_t)b * Nn;
        ab[tid] = e1 * inv + 1.f;
        ab[tid + 64] = e2 * inv + 1.f;
        if (tid < 3) ab[tid + 128] = e3 * inv + 1.f;
    }
}

// ---------------------------------------------------------------------------
// Transpose Graw head-slices: GrawT[bh][d][y] (y padded to 160 with zeros,
// stride YP). 64x64 LDS tiles, grid (4 d-tiles, 3 y-tiles, B*H).
// ---------------------------------------------------------------------------
__global__ __launch_bounds__(256) void transpose_kernel(
    const __hip_bfloat16* __restrict__ Gcat, __hip_bfloat16* __restrict__ GrawT)
{
    const int bh = blockIdx.z, b = bh >> 2, h = bh & 3;
    const int d0 = blockIdx.x * 64, y0 = blockIdx.y * 64;
    __shared__ short Ls[64 * 72];
    const int tid = threadIdx.x;
    const short* src = (const short*)Gcat + (size_t)b * Nn * OC + h * Dd + d0;
    short* dst = (short*)GrawT + (size_t)bh * 256 * YP + (size_t)d0 * YP;

    #pragma unroll
    for (int i = 0; i < 2; ++i) {
        const int task = i * 256 + tid;
        const int r = task >> 3, c8 = task & 7;
        const int y = y0 + r;
        bf16x8 v = {};
        if (y < Nn) v = *(const bf16x8*)(src + (size_t)y * OC + c8 * 8);
        *(bf16x8*)&Ls[r * 72 + c8 * 8] = v;
    }
    __syncthreads();
    #pragma unroll
    for (int i = 0; i < 2; ++i) {
        const int task = i * 256 + tid;
        const int dr = task >> 3, y8 = task & 7;
        const int yg = y0 + y8 * 8;
        if (yg < KAGG) {
            short tmp[8];
            #pragma unroll
            for (int j = 0; j < 8; ++j) tmp[j] = Ls[(y8 * 8 + j) * 72 + dr];
            *(bf16x8*)(dst + (size_t)dr * YP + yg) = *(bf16x8*)tmp;
        }
    }
}

// ---------------------------------------------------------------------------
// edge_mfma_rs (double-buffered): 64x64 tile edge attention + sigmoid +
// edge write + slotted partial rowsums. Grid (3 ytiles, 3 xtiles, B*H).
// Per wave per STAGE: 2 gload_lds -> counted s_waitcnt vmcnt(2).
// ---------------------------------------------------------------------------
__global__ __launch_bounds__(256) void edge_mfma_rs(
    const __hip_bfloat16* __restrict__ Gcat, const float* __restrict__ adj,
    float* __restrict__ edge, float* __restrict__ rs)
{
    const int bh = blockIdx.z;
    const int b = bh >> 2, h = bh & 3;
    const int x0 = blockIdx.y * 64, y0 = blockIdx.x * 64;
    __shared__ short Qs[2][64 * 32];
    __shared__ short Ks[2][64 * 32];
    const int tid = threadIdx.x;
    const int wave = tid >> 6, lane = tid & 63;
    const int wr = wave >> 1, wc = wave & 1;
    f32x4 acc[2][2] = {};
    const short* qbase = (const short*)Gcat + (size_t)b * Nn * OC + 2048 + h * Dd;
    const short* kbase = (const short*)Gcat + (size_t)b * Nn * OC + 1024 + h * Dd;
    const int lr = lane >> 2, lcs = (lane & 3) * 8;

    auto STAGE = [&](int buf, int k0) {
        const int c = wave;
        int xr = x0 + c * 16 + lr; if (xr > Nn - 1) xr = Nn - 1;
        gload_lds16(qbase + (size_t)xr * OC + k0 + lcs, &Qs[buf][c * 512]);
        int yr = y0 + c * 16 + lr; if (yr > Nn - 1) yr = Nn - 1;
        gload_lds16(kbase + (size_t)yr * OC + k0 + lcs, &Ks[buf][c * 512]);
    };

    STAGE(0, 0);                                   // 2 outstanding
    for (int t = 0; t < 8; ++t) {
        const int buf = t & 1;
        if (t < 7) {
            STAGE(buf ^ 1, (t + 1) * 32);          // +2 -> 4
            asm volatile("s_waitcnt vmcnt(2)" ::: "memory");
        } else {
            asm volatile("s_waitcnt vmcnt(0)" ::: "memory");
        }
        __builtin_amdgcn_s_barrier();
        __builtin_amdgcn_sched_barrier(0);
        bf16x8 qf[2], kf[2];
        #pragma unroll
        for (int i = 0; i < 2; ++i) {
            qf[i] = *(const bf16x8*)&Qs[buf][(wr * 32 + i * 16 + (lane & 15)) * 32 + (lane >> 4) * 8];
            kf[i] = *(const bf16x8*)&Ks[buf][(wc * 32 + i * 16 + (lane & 15)) * 32 + (lane >> 4) * 8];
        }
        __builtin_amdgcn_s_setprio(1);
        #pragma unroll
        for (int mi = 0; mi < 2; ++mi)
            #pragma unroll
            for (int ni = 0; ni < 2; ++ni)
                acc[mi][ni] = __builtin_amdgcn_mfma_f32_16x16x32_bf16(
                    qf[mi], kf[ni], acc[mi][ni], 0, 0, 0);
        __builtin_amdgcn_s_setprio(0);
        __builtin_amdgcn_sched_barrier(0);
        if (t < 7) __builtin_amdgcn_s_barrier();
    }

    const int cc = lane & 15;
    const int rg = (lane >> 4) * 4;
    const float* adjb = adj + (size_t)b * Nn * Nn;
    float* edgeb = edge + (size_t)bh * Nn * Nn;
    float* rsb = rs + ((size_t)(blockIdx.x * 2 + wc) * (Bb * Hh) + bh) * Nn;
    #pragma unroll
    for (int mi = 0; mi < 2; ++mi) {
        float rsum[4] = {0.f, 0.f, 0.f, 0.f};
        #pragma unroll
        for (int ni = 0; ni < 2; ++ni) {
            const int y = y0 + wc * 32 + ni * 16 + cc;
            #pragma unroll
            for (int r = 0; r < 4; ++r) {
                const int x = x0 + wr * 32 + mi * 16 + rg + r;
                const float e = 1.f / (1.f + __expf(-acc[mi][ni][r] * (1.f / 16.f)));
                if (x < Nn && y < Nn) {
                    edgeb[x * Nn + y] = e;
                    rsum[r] += adjb[x * Nn + y] * e;
                }
            }
        }
        #pragma unroll
        for (int r = 0; r < 4; ++r) {
            float v = rsum[r];
            v += __shfl_xor(v, 1); v += __shfl_xor(v, 2);
            v += __shfl_xor(v, 4); v += __shfl_xor(v, 8);
            const int x = x0 + wr * 32 + mi * 16 + rg + r;
            if (cc == 0 && x < Nn) rsb[x] = v;
        }
    }
}

// ---------------------------------------------------------------------------
// wbuild (dinv merged): one block per bh. dinv from 6 rs slots in LDS, then
// Wb[bh][x][y] = dinvx*(adj*edge + I)*dinv_y*att_y, bf16, y-pad 160.
// ---------------------------------------------------------------------------
__global__ __launch_bounds__(256) void wbuild_kernel(
    const float* __restrict__ adj, const float* __restrict__ edge,
    const float* __restrict__ rs, const float* __restrict__ att,
    __hip_bfloat16* __restrict__ Wb)
{
    const int bh = blockIdx.x, b = bh >> 2;
    __shared__ float dxL[Nn], daL[Nn];
    const int tid = threadIdx.x;
    if (tid < Nn) {
        float s = 0.f;
        #pragma unroll
        for (int sl = 0; sl < 6; ++sl)
            s += rs[(size_t)sl * (Bb * Hh * Nn) + (size_t)bh * Nn + tid];
        const float dv = rsqrtf(s + 1.f);
        dxL[tid] = dv;
        daL[tid] = dv * att[(size_t)b * Nn + tid];
    }
    __syncthreads();
    const float* ab = adj + (size_t)b * Nn * Nn;
    const float* eb = edge + (size_t)bh * Nn * Nn;
    short* wbb = (short*)Wb + (size_t)bh * XP * YP;
    for (int task = tid; task < Nn * 20; task += 256) {
        const int x = task / 20, g = task % 20;
        const float dx = dxL[x];
        short outv[8];
        #pragma unroll
        for (int j = 0; j < 8; ++j) {
            const int y = g * 8 + j;
            float w = 0.f;
            if (y < Nn) {
                float a = ab[x * Nn + y] * eb[x * Nn + y];
                if (x == y) a += 1.f;
                w = dx * a * daL[y];
            }
            __hip_bfloat16 hb = __float2bfloat16(w);
            outv[j] = *(short*)&hb;
        }
        *(bf16x8*)(wbb + (size_t)x * YP + g * 8) = *(bf16x8*)outv;
    }
}

// ---------------------------------------------------------------------------
// Aggregation MFMA: per (b,h), Gout[x][d] = sum_y Wb[x][y] * GrawT[d][y].
// ---------------------------------------------------------------------------
__global__ __launch_bounds__(512) void agg_mfma(
    const __hip_bfloat16* __restrict__ Wb, const __hip_bfloat16* __restrict__ GrawT,
    float* __restrict__ Gout)
{
    const int bh = blockIdx.x, b = bh >> 2, h = bh & 3;
    __shared__ short As[XP * 40];
    __shared__ short Bs[256 * 40];
    const int tid = threadIdx.x;
    const int wave = tid >> 6, lane = tid & 63;
    f32x4 acc[9][2] = {};
    const short* wsrc = (const short*)Wb + (size_t)bh * XP * YP;
    const short* gsrc = (const short*)GrawT + (size_t)bh * 256 * YP;

    for (int kc = 0; kc < 5; ++kc) {
        const int k0 = kc * 32;
        __syncthreads();
        #pragma unroll
        for (int i = 0; i < 2; ++i) {
            const int t = i * 512 + tid;
            if (t < 655) {
                const int row = t / 5, part = t - row * 5;
                gload_lds16(wsrc + (size_t)row * YP + k0 + part * 8,
                            &As[(i * 512 + (tid & ~63)) * 8]);
            }
        }
        #pragma unroll
        for (int i = 0; i < 3; ++i) {
            const int t = i * 512 + tid;
            if (t < 1280) {
                const int row = t / 5, part = t - row * 5;
                gload_lds16(gsrc + (size_t)row * YP + k0 + part * 8,
                            &Bs[(i * 512 + (tid & ~63)) * 8]);
            }
        }
        __syncthreads();
        bf16x8 af[9], bfr[2];
        #pragma unroll
        for (int mi = 0; mi < 9; ++mi)
            af[mi] = *(const bf16x8*)&As[(mi * 16 + (lane & 15)) * 40 + (lane >> 4) * 8];
        #pragma unroll
        for (int ni = 0; ni < 2; ++ni)
            bfr[ni] = *(const bf16x8*)&Bs[(wave * 32 + ni * 16 + (lane & 15)) * 40 + (lane >> 4) * 8];
        __builtin_amdgcn_s_setprio(1);
        #pragma unroll
        for (int mi = 0; mi < 9; ++mi)
            #pragma unroll
            for (int ni = 0; ni < 2; ++ni)
                acc[mi][ni] = __builtin_amdgcn_mfma_f32_16x16x32_bf16(
                    af[mi], bfr[ni], acc[mi][ni], 0, 0, 0);
        __builtin_amdgcn_s_setprio(0);
    }

    float* gob = Gout + (size_t)b * Nn * OUTF + h * Dd;
    #pragma unroll
    for (int mi = 0; mi < 9; ++mi)
        #pragma unroll
        for (int ni = 0; ni < 2; ++ni) {
            const int d = wave * 32 + ni * 16 + (lane & 15);
            #pragma unroll
            for (int r = 0; r < 4; ++r) {
                const int x = mi * 16 + (lane >> 4) * 4 + r;
                if (x < Nn) gob[(size_t)x * OUTF + d] = acc[mi][ni][r];
            }
        }
}

// ---------------------------------------------------------------------------
// global_node[b,o] = lrelu(b_gs + sum_n W_gs[n]*Gout[b,n,o]); build Z_in.
// ---------------------------------------------------------------------------
__global__ __launch_bounds__(256) void gn_kernel(
    const float* __restrict__ Gout, const float* __restrict__ Wgs,
    const float* __restrict__ bgs, const float* __restrict__ Tx,
    float* __restrict__ Zin)
{
    __shared__ float wgs[Nn];
    if (threadIdx.x < Nn) wgs[threadIdx.x] = Wgs[threadIdx.x];
    __syncthreads();
    const int idx = blockIdx.x * 256 + threadIdx.x;
    const int b = idx >> 10, o = idx & 1023;
    float s = bgs[0];
    const float* g = Gout + (size_t)b * Nn * OUTF + o;
    for (int n = 0; n < Nn; ++n) s += wgs[n] * g[(size_t)n * OUTF];
    Zin[(size_t)b * 2048 + o] = LRELU(s);
    Zin[(size_t)b * 2048 + 1024 + o] = Tx[(size_t)b * OUTF + o];
}

// ---------------------------------------------------------------------------
extern "C" void kernel_launch(void* const* d_in, const int* in_sizes, int n_in,
                              void* d_out, int out_size, void* d_ws, size_t ws_size,
                              hipStream_t stream) {
    const float* tab  = (const float*)d_in[0];
    const float* node = (const float*)d_in[1];
    const float* adj  = (const float*)d_in[2];
    const float* W_gx = (const float*)d_in[3];
    const float* b_gx = (const float*)d_in[4];
    const float* W_tx = (const float*)d_in[5];
    const float* b_tx = (const float*)d_in[6];
    const float* W_gk = (const float*)d_in[7];
    const float* W_tq = (const float*)d_in[8];
    const float* W_gq = (const float*)d_in[9];
    const float* W_gs = (const float*)d_in[10];
    const float* b_gs = (const float*)d_in[11];
    const float* W_zx = (const float*)d_in[12];
    const float* b_zx = (const float*)d_in[13];

    const size_t GX_ELEMS = (size_t)Bb * Nn * OUTF;   // 34,340,864
    const int M_NODE = Bb * Nn;                       // 33536

    float* out   = (float*)d_out;
    float* o_GX  = out;
    float* o_TX  = o_GX + GX_ELEMS;
    float* o_ZX  = o_TX + (size_t)Bb * OUTF;
    float* o_ATT = o_ZX + (size_t)Bb * OUTF;
    float* o_EDG = o_ATT + (size_t)Bb * Nn;

    // workspace: bf16 regions first, then fp32
    __hip_bfloat16* wb      = (__hip_bfloat16*)d_ws;
    __hip_bfloat16* w_nodeb = wb;                                          // 33536*512
    __hip_bfloat16* w_Wcat  = w_nodeb + (size_t)M_NODE * INF_;             // 3072*512
    __hip_bfloat16* w_Gcat  = w_Wcat + (size_t)OC * INF_;                  // 33536*3072
    __hip_bfloat16* w_GrawT = w_Gcat + (size_t)M_NODE * OC;                // 1024*256*168
    __hip_bfloat16* w_Wb    = w_GrawT + (size_t)Bb * Hh * 256 * YP;        // 1024*144*168
    float* wf       = (float*)(w_Wb + (size_t)Bb * Hh * XP * YP);
    float* w_Tq     = wf;
    float* w_Zin    = w_Tq + (size_t)Bb * OUTF;
    float* w_rs     = w_Zin + (size_t)Bb * 2 * OUTF;                       // 6*1024*131

    const dim3 blk(256);

    // 0. fp32 -> bf16
    convert_kernel<<<dim3(2048), blk, 0, stream>>>(node, W_gx, W_gk, W_gq,
                                                   w_nodeb, w_Wcat);
    // 1. tabular GEMMs
    gemm_aw<<<dim3(16, 4), blk, 0, stream>>>(tab, W_tx, b_tx, o_TX, Bb, INF_, OUTF);
    gemm_aw<<<dim3(16, 4), blk, 0, stream>>>(tab, W_tq, nullptr, w_Tq, Bb, INF_, OUTF);
    // 2. fused node GEMM -> Gcat bf16 [33536][3072] (1D grid, XCD swizzle)
    gemm_node_mfma<<<dim3(24 * 262), blk, 0, stream>>>(w_nodeb, w_Wcat, b_gx, w_Gcat);
    // 3. node attention -> o_ATT (softmax + 1)
    nodeatt_kernel<<<dim3(Bb), blk, 0, stream>>>(w_Tq, w_Gcat, o_ATT);
    // 4. transpose Graw head-slices -> GrawT
    transpose_kernel<<<dim3(4, 3, Bb * Hh), blk, 0, stream>>>(w_Gcat, w_GrawT);
    // 5. edge attention + slotted rowsums
    edge_mfma_rs<<<dim3(3, 3, Bb * Hh), blk, 0, stream>>>(w_Gcat, adj, o_EDG, w_rs);
    // 6. folded weight build (dinv merged) -> Wb
    wbuild_kernel<<<dim3(Bb * Hh), blk, 0, stream>>>(adj, o_EDG, w_rs, o_ATT, w_Wb);
    // 7. aggregation MFMA -> o_GX
    agg_mfma<<<dim3(Bb * Hh), dim3(512), 0, stream>>>(w_Wb, w_GrawT, o_GX);
    // 8. graph summary + Z_in build
    gn_kernel<<<dim3((Bb * OUTF) / 256), blk, 0, stream>>>(o_GX, W_gs, b_gs, o_TX, w_Zin);
    // 9. final Z GEMM
    gemm_aw<<<dim3(16, 4), blk, 0, stream>>>(w_Zin, W_zx, b_zx, o_ZX, Bb, 2 * OUTF, OUTF);
}

// Round 6
// 685.117 us; speedup vs baseline: 4.1681x; 1.0634x over previous
//
#include <hip/hip_runtime.h>
#include <hip/hip_bf16.h>
#include <math.h>

// Dynamic_MHGCN_FusionLayer: B=256, N=131, IN=512, OUT=1024, H=4, D=256
// Round 6: gemm_node -> single-buffer BK=64 with bank-conflict XOR swizzle
// (pre-swizzled global src + swizzled ds_read, LDS linear) and LDS-staged
// vectorized epilogue. gn colsum fused into agg_mfma. Edge reads swizzled.
// Tabular GEMMs merged into one launch.

#define LRELU(x) ((x) > 0.f ? (x) : 0.01f * (x))

constexpr int Bb = 256;
constexpr int Nn = 131;
constexpr int INF_ = 512;
constexpr int OUTF = 1024;
constexpr int Hh = 4;
constexpr int Dd = 256;
constexpr int OC = 3072;   // Graw(0..1023) | Gk(1024..2047) | Gq(2048..3071)
constexpr int YP = 168;    // padded y-stride (shorts) for Wb / GrawT rows
constexpr int KAGG = 160;  // padded K (y) for aggregation GEMM
constexpr int XP = 144;    // padded x rows for Wb

typedef __attribute__((ext_vector_type(8))) short bf16x8;
typedef __attribute__((ext_vector_type(4))) float f32x4;

__device__ __forceinline__ float bf2f(short s) {
    union { float f; unsigned u; } c;
    c.u = ((unsigned)(unsigned short)s) << 16;
    return c.f;
}

__device__ __forceinline__ void gload_lds16(const void* g, void* lds) {
    __builtin_amdgcn_global_load_lds(
        (const __attribute__((address_space(1))) void*)g,
        (__attribute__((address_space(3))) void*)lds, 16, 0, 0);
}

// ---------------------------------------------------------------------------
// fp32 -> bf16 conversion: node_feats and the packed weight matrix Wcat.
// ---------------------------------------------------------------------------
__global__ __launch_bounds__(256) void convert_kernel(
    const float* __restrict__ node, const float* __restrict__ Wgx,
    const float* __restrict__ Wgk, const float* __restrict__ Wgq,
    __hip_bfloat16* __restrict__ node_bf, __hip_bfloat16* __restrict__ Wcat)
{
    const size_t NE = (size_t)Bb * Nn * INF_ / 4;
    const size_t WE = (size_t)OC * INF_ / 4;
    for (size_t i = (size_t)blockIdx.x * 256 + threadIdx.x; i < NE + WE;
         i += (size_t)gridDim.x * 256) {
        if (i < NE) {
            const float4 v = ((const float4*)node)[i];
            __hip_bfloat16* o = node_bf + i * 4;
            o[0] = __float2bfloat16(v.x); o[1] = __float2bfloat16(v.y);
            o[2] = __float2bfloat16(v.z); o[3] = __float2bfloat16(v.w);
        } else {
            const size_t j = i - NE;
            const size_t which = j / (1024 * INF_ / 4);
            const float* src = (which == 0) ? Wgx : (which == 1 ? Wgk : Wgq);
            const size_t srcj = j - which * (1024 * INF_ / 4);
            const float4 v = ((const float4*)src)[srcj];
            __hip_bfloat16* o = Wcat + j * 4;
            o[0] = __float2bfloat16(v.x); o[1] = __float2bfloat16(v.y);
            o[2] = __float2bfloat16(v.z); o[3] = __float2bfloat16(v.w);
        }
    }
}

// ---------------------------------------------------------------------------
// Fused node GEMM (bf16 MFMA), single-buffer BK=64, bank-conflict swizzle:
// LDS logical [row][k] with k-granule g stored at slot g ^ (row&7); achieved
// by pre-swizzling the per-lane GLOBAL source (LDS dest stays linear) and
// XOR-ing the ds_read address. Epilogue staged through LDS -> bf16x8 stores.
// Grid 1D 6288 = 24 o-tiles x 262 m-tiles, XCD-bijective swizzle.
// ---------------------------------------------------------------------------
__global__ __launch_bounds__(256) void gemm_node_mfma(
    const __hip_bfloat16* __restrict__ A, const __hip_bfloat16* __restrict__ W,
    const float* __restrict__ bias_gx, __hip_bfloat16* __restrict__ Gcat)
{
    __shared__ short SM[16384];          // As=[0,8192) Bs=[8192,16384) shorts
    short* As = SM;
    short* Bs = SM + 8192;
    const int tid = threadIdx.x;
    const int wave = tid >> 6, lane = tid & 63;
    const int swz = (blockIdx.x & 7) * 786 + (blockIdx.x >> 3);
    const int o0 = (swz % 24) * 128;
    const int m0 = (swz / 24) * 128;
    const int wr = wave >> 1, wc = wave & 1;

    f32x4 acc[4][4] = {};
    const short* Asrc = (const short*)A;
    const short* Wsrc = (const short*)W;
    // staging: LDS slot (row, lane&7) receives global granule (lane&7)^(lane>>3)
    const int g_src = ((lane & 7) ^ (lane >> 3)) * 8;   // shorts
    const int srow = tid >> 3;                          // + j*32

    for (int t = 0; t < 8; ++t) {
        const int k0 = t * 64;
        #pragma unroll
        for (int j = 0; j < 4; ++j) {
            const int row = j * 32 + srow;
            gload_lds16(Asrc + (size_t)(m0 + row) * INF_ + k0 + g_src,
                        &As[(j * 256 + (tid & ~63)) * 8]);
            gload_lds16(Wsrc + (size_t)(o0 + row) * INF_ + k0 + g_src,
                        &Bs[(j * 256 + (tid & ~63)) * 8]);
        }
        __syncthreads();
        #pragma unroll
        for (int ks = 0; ks < 2; ++ks) {
            const int sa = ((ks * 4 + (lane >> 4)) ^ (lane & 7)) * 8;
            bf16x8 af[4], bfr[4];
            #pragma unroll
            for (int i = 0; i < 4; ++i) {
                const int Ra = wr * 64 + i * 16 + (lane & 15);
                af[i] = *(const bf16x8*)&As[Ra * 64 + sa];
                const int Rb = wc * 64 + i * 16 + (lane & 15);
                bfr[i] = *(const bf16x8*)&Bs[Rb * 64 + sa];
            }
            #pragma unroll
            for (int mi = 0; mi < 4; ++mi)
                #pragma unroll
                for (int ni = 0; ni < 4; ++ni)
                    acc[mi][ni] = __builtin_amdgcn_mfma_f32_16x16x32_bf16(
                        af[mi], bfr[ni], acc[mi][ni], 0, 0, 0);
        }
        __syncthreads();
    }

    // epilogue: bias+lrelu -> LDS [128][128] (col-granule XOR swizzle) ->
    // coalesced bf16x8 global stores.
    const int cc = lane & 15;
    const int rg = (lane >> 4) * 4;
    #pragma unroll
    for (int mi = 0; mi < 4; ++mi)
        #pragma unroll
        for (int ni = 0; ni < 4; ++ni) {
            const int col = wc * 64 + ni * 16 + cc;
            const int o = o0 + col;
            const float badd = (o < OUTF) ? bias_gx[o] : 0.f;
            #pragma unroll
            for (int r = 0; r < 4; ++r) {
                const int row = wr * 64 + mi * 16 + rg + r;
                float v = acc[mi][ni][r] + badd;
                v = LRELU(v);
                __hip_bfloat16 hb = __float2bfloat16(v);
                const int slot = (col >> 3) ^ (row & 7);
                SM[row * 128 + slot * 8 + (col & 7)] = *(short*)&hb;
            }
        }
    __syncthreads();
    #pragma unroll
    for (int j = 0; j < 8; ++j) {
        const int G = j * 256 + tid;
        const int row = G >> 4, gc = G & 15;
        const int slot = gc ^ (row & 7);
        *(bf16x8*)((short*)Gcat + (size_t)(m0 + row) * OC + o0 + gc * 8) =
            *(const bf16x8*)&SM[row * 128 + slot * 8];
    }
}

// ---------------------------------------------------------------------------
// Merged tabular GEMMs (fp32): which=0 -> T_X (bias b_tx), which=1 -> T_q.
// C[m,o] = lrelu(sum_k tab[m,k]*W[o,k] + bias). Grid (32,4).
// ---------------------------------------------------------------------------
__global__ __launch_bounds__(256) void gemm_tab(
    const float* __restrict__ Atab, const float* __restrict__ Wtx,
    const float* __restrict__ btx, const float* __restrict__ Wtq,
    float* __restrict__ Ctx, float* __restrict__ Ctq)
{
    const int which = blockIdx.x >> 4;
    const float* Wm = which ? Wtq : Wtx;
    float* C = which ? Ctq : Ctx;
    __shared__ float As[16][68];
    __shared__ float Ws[16][68];
    const int tid = threadIdx.x;
    const int tx = tid & 15;
    const int ty = tid >> 4;
    const int m0 = blockIdx.y * 64;
    const int o0 = (blockIdx.x & 15) * 64;

    float acc[4][4] = {};
    for (int k0 = 0; k0 < INF_; k0 += 16) {
        const int j = tid & 15;
        const int i = tid >> 4;
        #pragma unroll
        for (int r = 0; r < 4; ++r)
            As[j][i + 16 * r] = Atab[(size_t)(m0 + i + 16 * r) * INF_ + k0 + j];
        #pragma unroll
        for (int r = 0; r < 4; ++r)
            Ws[j][i + 16 * r] = Wm[(size_t)(o0 + i + 16 * r) * INF_ + k0 + j];
        __syncthreads();
        #pragma unroll
        for (int kk = 0; kk < 16; ++kk) {
            const float4 av = *(const float4*)&As[kk][ty * 4];
            const float4 wv = *(const float4*)&Ws[kk][tx * 4];
            const float a[4] = {av.x, av.y, av.z, av.w};
            const float w[4] = {wv.x, wv.y, wv.z, wv.w};
            #pragma unroll
            for (int r = 0; r < 4; ++r)
                #pragma unroll
                for (int c = 0; c < 4; ++c)
                    acc[r][c] += a[r] * w[c];
        }
        __syncthreads();
    }
    #pragma unroll
    for (int r = 0; r < 4; ++r) {
        const int m = m0 + ty * 4 + r;
        const int o = o0 + tx * 4;
        float4 v;
        float* vp = (float*)&v;
        #pragma unroll
        for (int c = 0; c < 4; ++c) {
            float t = acc[r][c] + (which ? 0.f : btx[o + c]);
            vp[c] = LRELU(t);
        }
        *(float4*)&C[(size_t)m * OUTF + o] = v;
    }
}

// ---------------------------------------------------------------------------
// Generic fp32 tiled GEMM (final Z GEMM only).
// ---------------------------------------------------------------------------
__global__ __launch_bounds__(256) void gemm_aw(
    const float* __restrict__ A, const float* __restrict__ W,
    const float* __restrict__ bias, float* __restrict__ C,
    int M, int K, int O)
{
    __shared__ float As[16][68];
    __shared__ float Ws[16][68];
    const int tid = threadIdx.x;
    const int tx = tid & 15;
    const int ty = tid >> 4;
    const int m0 = blockIdx.y * 64;
    const int o0 = blockIdx.x * 64;

    float acc[4][4] = {};
    for (int k0 = 0; k0 < K; k0 += 16) {
        const int j = tid & 15;
        const int i = tid >> 4;
        #pragma unroll
        for (int r = 0; r < 4; ++r)
            As[j][i + 16 * r] = A[(size_t)(m0 + i + 16 * r) * K + k0 + j];
        #pragma unroll
        for (int r = 0; r < 4; ++r)
            Ws[j][i + 16 * r] = W[(size_t)(o0 + i + 16 * r) * K + k0 + j];
        __syncthreads();
        #pragma unroll
        for (int kk = 0; kk < 16; ++kk) {
            const float4 av = *(const float4*)&As[kk][ty * 4];
            const float4 wv = *(const float4*)&Ws[kk][tx * 4];
            const float a[4] = {av.x, av.y, av.z, av.w};
            const float w[4] = {wv.x, wv.y, wv.z, wv.w};
            #pragma unroll
            for (int r = 0; r < 4; ++r)
                #pragma unroll
                for (int c = 0; c < 4; ++c)
                    acc[r][c] += a[r] * w[c];
        }
        __syncthreads();
    }
    #pragma unroll
    for (int r = 0; r < 4; ++r) {
        const int m = m0 + ty * 4 + r;
        const int o = o0 + tx * 4;
        float4 v;
        float* vp = (float*)&v;
        #pragma unroll
        for (int c = 0; c < 4; ++c) {
            float t = acc[r][c] + (bias ? bias[o + c] : 0.f);
            vp[c] = LRELU(t);
        }
        *(float4*)&C[(size_t)m * O + o] = v;
    }
}

// ---------------------------------------------------------------------------
// node_att softmax: s[b,n] = (1/32) * Tq[b,:] . Gk[b,n,:]; softmax over n; +1.
// ---------------------------------------------------------------------------
__global__ __launch_bounds__(256) void nodeatt_kernel(
    const float* __restrict__ Tq, const __hip_bfloat16* __restrict__ Gcat,
    float* __restrict__ att)
{
    const int b = blockIdx.x;
    __shared__ float tq[OUTF];
    __shared__ float sc[136];
    const int tid = threadIdx.x;
    for (int o = tid; o < OUTF; o += 256) tq[o] = Tq[(size_t)b * OUTF + o];
    __syncthreads();

    const int wave = tid >> 6, lane = tid & 63;
    for (int n = wave; n < Nn; n += 4) {
        const short4* gk = (const short4*)((const short*)Gcat + ((size_t)b * Nn + n) * OC + 1024);
        float s = 0.f;
        for (int o4 = lane; o4 < 256; o4 += 64) {
            const short4 v = gk[o4];
            s += tq[o4 * 4 + 0] * bf2f(v.x) + tq[o4 * 4 + 1] * bf2f(v.y)
               + tq[o4 * 4 + 2] * bf2f(v.z) + tq[o4 * 4 + 3] * bf2f(v.w);
        }
        #pragma unroll
        for (int off = 32; off; off >>= 1) s += __shfl_xor(s, off);
        if (lane == 0) sc[n] = s * (1.f / 32.f);
    }
    __syncthreads();

    if (tid < 64) {
        const float v1 = sc[tid];
        const float v2 = sc[tid + 64];
        const float v3 = (tid < 3) ? sc[tid + 128] : -1e30f;
        float m = fmaxf(fmaxf(v1, v2), v3);
        #pragma unroll
        for (int off = 32; off; off >>= 1) m = fmaxf(m, __shfl_xor(m, off));
        const float e1 = expf(v1 - m);
        const float e2 = expf(v2 - m);
        const float e3 = (tid < 3) ? expf(v3 - m) : 0.f;
        float s = e1 + e2 + e3;
        #pragma unroll
        for (int off = 32; off; off >>= 1) s += __shfl_xor(s, off);
        const float inv = 1.f / s;
        float* ab = att + (size_t)b * Nn;
        ab[tid] = e1 * inv + 1.f;
        ab[tid + 64] = e2 * inv + 1.f;
        if (tid < 3) ab[tid + 128] = e3 * inv + 1.f;
    }
}

// ---------------------------------------------------------------------------
// Transpose Graw head-slices: GrawT[bh][d][y] (y padded to 160 with zeros,
// stride YP). 64x64 LDS tiles, grid (4 d-tiles, 3 y-tiles, B*H).
// ---------------------------------------------------------------------------
__global__ __launch_bounds__(256) void transpose_kernel(
    const __hip_bfloat16* __restrict__ Gcat, __hip_bfloat16* __restrict__ GrawT)
{
    const int bh = blockIdx.z, b = bh >> 2, h = bh & 3;
    const int d0 = blockIdx.x * 64, y0 = blockIdx.y * 64;
    __shared__ short Ls[64 * 72];
    const int tid = threadIdx.x;
    const short* src = (const short*)Gcat + (size_t)b * Nn * OC + h * Dd + d0;
    short* dst = (short*)GrawT + (size_t)bh * 256 * YP + (size_t)d0 * YP;

    #pragma unroll
    for (int i = 0; i < 2; ++i) {
        const int task = i * 256 + tid;
        const int r = task >> 3, c8 = task & 7;
        const int y = y0 + r;
        bf16x8 v = {};
        if (y < Nn) v = *(const bf16x8*)(src + (size_t)y * OC + c8 * 8);
        *(bf16x8*)&Ls[r * 72 + c8 * 8] = v;
    }
    __syncthreads();
    #pragma unroll
    for (int i = 0; i < 2; ++i) {
        const int task = i * 256 + tid;
        const int dr = task >> 3, y8 = task & 7;
        const int yg = y0 + y8 * 8;
        if (yg < KAGG) {
            short tmp[8];
            #pragma unroll
            for (int j = 0; j < 8; ++j) tmp[j] = Ls[(y8 * 8 + j) * 72 + dr];
            *(bf16x8*)(dst + (size_t)dr * YP + yg) = *(bf16x8*)tmp;
        }
    }
}

// ---------------------------------------------------------------------------
// edge_mfma_rs (double-buffered, swizzled reads): 64x64 tile edge attention +
// sigmoid + edge write + slotted partial rowsums. Grid (3 yt, 3 xt, B*H).
// ---------------------------------------------------------------------------
__global__ __launch_bounds__(256) void edge_mfma_rs(
    const __hip_bfloat16* __restrict__ Gcat, const float* __restrict__ adj,
    float* __restrict__ edge, float* __restrict__ rs)
{
    const int bh = blockIdx.z;
    const int b = bh >> 2, h = bh & 3;
    const int x0 = blockIdx.y * 64, y0 = blockIdx.x * 64;
    __shared__ short Qs[2][64 * 32];
    __shared__ short Ks[2][64 * 32];
    const int tid = threadIdx.x;
    const int wave = tid >> 6, lane = tid & 63;
    const int wr = wave >> 1, wc = wave & 1;
    f32x4 acc[2][2] = {};
    const short* qbase = (const short*)Gcat + (size_t)b * Nn * OC + 2048 + h * Dd;
    const short* kbase = (const short*)Gcat + (size_t)b * Nn * OC + 1024 + h * Dd;
    const int lr = lane >> 2;
    // swizzled source granule: slot lane&3 holds g = (lane&3)^((lane>>3)&3)
    const int g_src = ((lane & 3) ^ ((lane >> 3) & 3)) * 8;

    auto STAGE = [&](int buf, int k0) {
        const int c = wave;
        int xr = x0 + c * 16 + lr; if (xr > Nn - 1) xr = Nn - 1;
        gload_lds16(qbase + (size_t)xr * OC + k0 + g_src, &Qs[buf][c * 512]);
        int yr = y0 + c * 16 + lr; if (yr > Nn - 1) yr = Nn - 1;
        gload_lds16(kbase + (size_t)yr * OC + k0 + g_src, &Ks[buf][c * 512]);
    };

    STAGE(0, 0);
    for (int t = 0; t < 8; ++t) {
        const int buf = t & 1;
        if (t < 7) {
            STAGE(buf ^ 1, (t + 1) * 32);
            asm volatile("s_waitcnt vmcnt(2)" ::: "memory");
        } else {
            asm volatile("s_waitcnt vmcnt(0)" ::: "memory");
        }
        __builtin_amdgcn_s_barrier();
        __builtin_amdgcn_sched_barrier(0);
        const int sa = ((lane >> 4) ^ ((lane >> 1) & 3)) * 8;
        bf16x8 qf[2], kf[2];
        #pragma unroll
        for (int i = 0; i < 2; ++i) {
            qf[i] = *(const bf16x8*)&Qs[buf][(wr * 32 + i * 16 + (lane & 15)) * 32 + sa];
            kf[i] = *(const bf16x8*)&Ks[buf][(wc * 32 + i * 16 + (lane & 15)) * 32 + sa];
        }
        __builtin_amdgcn_s_setprio(1);
        #pragma unroll
        for (int mi = 0; mi < 2; ++mi)
            #pragma unroll
            for (int ni = 0; ni < 2; ++ni)
                acc[mi][ni] = __builtin_amdgcn_mfma_f32_16x16x32_bf16(
                    qf[mi], kf[ni], acc[mi][ni], 0, 0, 0);
        __builtin_amdgcn_s_setprio(0);
        __builtin_amdgcn_sched_barrier(0);
        if (t < 7) __builtin_amdgcn_s_barrier();
    }

    const int cc = lane & 15;
    const int rg = (lane >> 4) * 4;
    const float* adjb = adj + (size_t)b * Nn * Nn;
    float* edgeb = edge + (size_t)bh * Nn * Nn;
    float* rsb = rs + ((size_t)(blockIdx.x * 2 + wc) * (Bb * Hh) + bh) * Nn;
    #pragma unroll
    for (int mi = 0; mi < 2; ++mi) {
        float rsum[4] = {0.f, 0.f, 0.f, 0.f};
        #pragma unroll
        for (int ni = 0; ni < 2; ++ni) {
            const int y = y0 + wc * 32 + ni * 16 + cc;
            #pragma unroll
            for (int r = 0; r < 4; ++r) {
                const int x = x0 + wr * 32 + mi * 16 + rg + r;
                const float e = 1.f / (1.f + __expf(-acc[mi][ni][r] * (1.f / 16.f)));
                if (x < Nn && y < Nn) {
                    edgeb[x * Nn + y] = e;
                    rsum[r] += adjb[x * Nn + y] * e;
                }
            }
        }
        #pragma unroll
        for (int r = 0; r < 4; ++r) {
            float v = rsum[r];
            v += __shfl_xor(v, 1); v += __shfl_xor(v, 2);
            v += __shfl_xor(v, 4); v += __shfl_xor(v, 8);
            const int x = x0 + wr * 32 + mi * 16 + rg + r;
            if (cc == 0 && x < Nn) rsb[x] = v;
        }
    }
}

// ---------------------------------------------------------------------------
// wbuild (dinv merged): one block per bh. dinv from 6 rs slots in LDS, then
// Wb[bh][x][y] = dinvx*(adj*edge + I)*dinv_y*att_y, bf16, y-pad 160.
// ---------------------------------------------------------------------------
__global__ __launch_bounds__(256) void wbuild_kernel(
    const float* __restrict__ adj, const float* __restrict__ edge,
    const float* __restrict__ rs, const float* __restrict__ att,
    __hip_bfloat16* __restrict__ Wb)
{
    const int bh = blockIdx.x, b = bh >> 2;
    __shared__ float dxL[Nn], daL[Nn];
    const int tid = threadIdx.x;
    if (tid < Nn) {
        float s = 0.f;
        #pragma unroll
        for (int sl = 0; sl < 6; ++sl)
            s += rs[(size_t)sl * (Bb * Hh * Nn) + (size_t)bh * Nn + tid];
        const float dv = rsqrtf(s + 1.f);
        dxL[tid] = dv;
        daL[tid] = dv * att[(size_t)b * Nn + tid];
    }
    __syncthreads();
    const float* ab = adj + (size_t)b * Nn * Nn;
    const float* eb = edge + (size_t)bh * Nn * Nn;
    short* wbb = (short*)Wb + (size_t)bh * XP * YP;
    for (int task = tid; task < Nn * 20; task += 256) {
        const int x = task / 20, g = task % 20;
        const float dx = dxL[x];
        short outv[8];
        #pragma unroll
        for (int j = 0; j < 8; ++j) {
            const int y = g * 8 + j;
            float w = 0.f;
            if (y < Nn) {
                float a = ab[x * Nn + y] * eb[x * Nn + y];
                if (x == y) a += 1.f;
                w = dx * a * daL[y];
            }
            __hip_bfloat16 hb = __float2bfloat16(w);
            outv[j] = *(short*)&hb;
        }
        *(bf16x8*)(wbb + (size_t)x * YP + g * 8) = *(bf16x8*)outv;
    }
}

// ---------------------------------------------------------------------------
// Aggregation MFMA + fused graph-summary colsum:
// Gout[x][d] = sum_y Wb[x][y]*GrawT[d][y]; gnode[b][h*256+d] = sum_x wgs[x]*Gout.
// ---------------------------------------------------------------------------
__global__ __launch_bounds__(512) void agg_mfma(
    const __hip_bfloat16* __restrict__ Wb, const __hip_bfloat16* __restrict__ GrawT,
    const float* __restrict__ Wgs, float* __restrict__ Gout,
    float* __restrict__ gnode)
{
    const int bh = blockIdx.x, b = bh >> 2, h = bh & 3;
    __shared__ short As[XP * 40];
    __shared__ short Bs[256 * 40];
    __shared__ float wgsL[Nn];
    const int tid = threadIdx.x;
    const int wave = tid >> 6, lane = tid & 63;
    if (tid < Nn) wgsL[tid] = Wgs[tid];
    f32x4 acc[9][2] = {};
    const short* wsrc = (const short*)Wb + (size_t)bh * XP * YP;
    const short* gsrc = (const short*)GrawT + (size_t)bh * 256 * YP;

    for (int kc = 0; kc < 5; ++kc) {
        const int k0 = kc * 32;
        __syncthreads();
        #pragma unroll
        for (int i = 0; i < 2; ++i) {
            const int t = i * 512 + tid;
            if (t < 655) {
                const int row = t / 5, part = t - row * 5;
                gload_lds16(wsrc + (size_t)row * YP + k0 + part * 8,
                            &As[(i * 512 + (tid & ~63)) * 8]);
            }
        }
        #pragma unroll
        for (int i = 0; i < 3; ++i) {
            const int t = i * 512 + tid;
            if (t < 1280) {
                const int row = t / 5, part = t - row * 5;
                gload_lds16(gsrc + (size_t)row * YP + k0 + part * 8,
                            &Bs[(i * 512 + (tid & ~63)) * 8]);
            }
        }
        __syncthreads();
        bf16x8 af[9], bfr[2];
        #pragma unroll
        for (int mi = 0; mi < 9; ++mi)
            af[mi] = *(const bf16x8*)&As[(mi * 16 + (lane & 15)) * 40 + (lane >> 4) * 8];
        #pragma unroll
        for (int ni = 0; ni < 2; ++ni)
            bfr[ni] = *(const bf16x8*)&Bs[(wave * 32 + ni * 16 + (lane & 15)) * 40 + (lane >> 4) * 8];
        __builtin_amdgcn_s_setprio(1);
        #pragma unroll
        for (int mi = 0; mi < 9; ++mi)
            #pragma unroll
            for (int ni = 0; ni < 2; ++ni)
                acc[mi][ni] = __builtin_amdgcn_mfma_f32_16x16x32_bf16(
                    af[mi], bfr[ni], acc[mi][ni], 0, 0, 0);
        __builtin_amdgcn_s_setprio(0);
    }

    float* gob = Gout + (size_t)b * Nn * OUTF + h * Dd;
    float gp[2] = {0.f, 0.f};
    #pragma unroll
    for (int mi = 0; mi < 9; ++mi)
        #pragma unroll
        for (int ni = 0; ni < 2; ++ni) {
            const int d = wave * 32 + ni * 16 + (lane & 15);
            #pragma unroll
            for (int r = 0; r < 4; ++r) {
                const int x = mi * 16 + (lane >> 4) * 4 + r;
                if (x < Nn) {
                    gob[(size_t)x * OUTF + d] = acc[mi][ni][r];
                    gp[ni] += wgsL[x] * acc[mi][ni][r];
                }
            }
        }
    #pragma unroll
    for (int ni = 0; ni < 2; ++ni) {
        gp[ni] += __shfl_xor(gp[ni], 16);
        gp[ni] += __shfl_xor(gp[ni], 32);
        if (lane < 16)
            gnode[(size_t)b * OUTF + h * Dd + wave * 32 + ni * 16 + lane] = gp[ni];
    }
}

// ---------------------------------------------------------------------------
// Zin build: Zin[b][0:1024] = lrelu(gnode + bgs), Zin[b][1024:2048] = T_X.
// ---------------------------------------------------------------------------
__global__ __launch_bounds__(256) void zin_build(
    const float* __restrict__ gnode, const float* __restrict__ bgs,
    const float* __restrict__ Tx, float* __restrict__ Zin)
{
    const int idx = blockIdx.x * 256 + threadIdx.x;
    const int b = idx >> 10, o = idx & 1023;
    const float s = gnode[idx] + bgs[0];
    Zin[(size_t)b * 2048 + o] = LRELU(s);
    Zin[(size_t)b * 2048 + 1024 + o] = Tx[idx];
}

// ---------------------------------------------------------------------------
extern "C" void kernel_launch(void* const* d_in, const int* in_sizes, int n_in,
                              void* d_out, int out_size, void* d_ws, size_t ws_size,
                              hipStream_t stream) {
    const float* tab  = (const float*)d_in[0];
    const float* node = (const float*)d_in[1];
    const float* adj  = (const float*)d_in[2];
    const float* W_gx = (const float*)d_in[3];
    const float* b_gx = (const float*)d_in[4];
    const float* W_tx = (const float*)d_in[5];
    const float* b_tx = (const float*)d_in[6];
    const float* W_gk = (const float*)d_in[7];
    const float* W_tq = (const float*)d_in[8];
    const float* W_gq = (const float*)d_in[9];
    const float* W_gs = (const float*)d_in[10];
    const float* b_gs = (const float*)d_in[11];
    const float* W_zx = (const float*)d_in[12];
    const float* b_zx = (const float*)d_in[13];

    const size_t GX_ELEMS = (size_t)Bb * Nn * OUTF;   // 34,340,864
    const int M_NODE = Bb * Nn;                       // 33536

    float* out   = (float*)d_out;
    float* o_GX  = out;
    float* o_TX  = o_GX + GX_ELEMS;
    float* o_ZX  = o_TX + (size_t)Bb * OUTF;
    float* o_ATT = o_ZX + (size_t)Bb * OUTF;
    float* o_EDG = o_ATT + (size_t)Bb * Nn;

    // workspace: bf16 regions first, then fp32
    __hip_bfloat16* wb      = (__hip_bfloat16*)d_ws;
    __hip_bfloat16* w_nodeb = wb;                                          // 33536*512
    __hip_bfloat16* w_Wcat  = w_nodeb + (size_t)M_NODE * INF_;             // 3072*512
    __hip_bfloat16* w_Gcat  = w_Wcat + (size_t)OC * INF_;                  // 33536*3072
    __hip_bfloat16* w_GrawT = w_Gcat + (size_t)M_NODE * OC;                // 1024*256*168
    __hip_bfloat16* w_Wb    = w_GrawT + (size_t)Bb * Hh * 256 * YP;        // 1024*144*168
    float* wf       = (float*)(w_Wb + (size_t)Bb * Hh * XP * YP);
    float* w_Tq     = wf;
    float* w_Zin    = w_Tq + (size_t)Bb * OUTF;
    float* w_rs     = w_Zin + (size_t)Bb * 2 * OUTF;                       // 6*1024*131
    float* w_gnode  = w_rs + (size_t)6 * Bb * Hh * Nn;                     // 256*1024

    const dim3 blk(256);

    // 0. fp32 -> bf16
    convert_kernel<<<dim3(2048), blk, 0, stream>>>(node, W_gx, W_gk, W_gq,
                                                   w_nodeb, w_Wcat);
    // 1. merged tabular GEMMs (T_X + T_q)
    gemm_tab<<<dim3(32, 4), blk, 0, stream>>>(tab, W_tx, b_tx, W_tq, o_TX, w_Tq);
    // 2. fused node GEMM -> Gcat bf16 [33536][3072]
    gemm_node_mfma<<<dim3(24 * 262), blk, 0, stream>>>(w_nodeb, w_Wcat, b_gx, w_Gcat);
    // 3. node attention -> o_ATT (softmax + 1)
    nodeatt_kernel<<<dim3(Bb), blk, 0, stream>>>(w_Tq, w_Gcat, o_ATT);
    // 4. transpose Graw head-slices -> GrawT
    transpose_kernel<<<dim3(4, 3, Bb * Hh), blk, 0, stream>>>(w_Gcat, w_GrawT);
    // 5. edge attention + slotted rowsums
    edge_mfma_rs<<<dim3(3, 3, Bb * Hh), blk, 0, stream>>>(w_Gcat, adj, o_EDG, w_rs);
    // 6. folded weight build (dinv merged) -> Wb
    wbuild_kernel<<<dim3(Bb * Hh), blk, 0, stream>>>(adj, o_EDG, w_rs, o_ATT, w_Wb);
    // 7. aggregation MFMA + fused gn colsum -> o_GX, gnode
    agg_mfma<<<dim3(Bb * Hh), dim3(512), 0, stream>>>(w_Wb, w_GrawT, W_gs,
                                                      o_GX, w_gnode);
    // 8. Zin build
    zin_build<<<dim3((Bb * OUTF) / 256), blk, 0, stream>>>(w_gnode, b_gs, o_TX, w_Zin);
    // 9. final Z GEMM
    gemm_aw<<<dim3(16, 4), blk, 0, stream>>>(w_Zin, W_zx, b_zx, o_ZX, Bb, 2 * OUTF, OUTF);
}

// Round 7
// 677.500 us; speedup vs baseline: 4.2150x; 1.0112x over previous
//
#include <hip/hip_runtime.h>
#include <hip/hip_bf16.h>
#include <math.h>

// Dynamic_MHGCN_FusionLayer: B=256, N=131, IN=512, OUT=1024, H=4, D=256
// Round 7: gemm_node ported to a 256x256 8-wave deep-pipelined schedule:
// BK=64 dbuf (128 KB LDS), XOR granule swizzle (validated conflict-free in R6),
// STAGE-early + single counted-drain barrier per K-tile, setprio MFMA clusters,
// bijective XCD swizzle. Direct stores (no LDS epilogue). Rest unchanged.

#define LRELU(x) ((x) > 0.f ? (x) : 0.01f * (x))

constexpr int Bb = 256;
constexpr int Nn = 131;
constexpr int INF_ = 512;
constexpr int OUTF = 1024;
constexpr int Hh = 4;
constexpr int Dd = 256;
constexpr int OC = 3072;   // Graw(0..1023) | Gk(1024..2047) | Gq(2048..3071)
constexpr int YP = 168;    // padded y-stride (shorts) for Wb / GrawT rows
constexpr int KAGG = 160;  // padded K (y) for aggregation GEMM
constexpr int XP = 144;    // padded x rows for Wb

typedef __attribute__((ext_vector_type(8))) short bf16x8;
typedef __attribute__((ext_vector_type(4))) float f32x4;

__device__ __forceinline__ float bf2f(short s) {
    union { float f; unsigned u; } c;
    c.u = ((unsigned)(unsigned short)s) << 16;
    return c.f;
}

__device__ __forceinline__ void gload_lds16(const void* g, void* lds) {
    __builtin_amdgcn_global_load_lds(
        (const __attribute__((address_space(1))) void*)g,
        (__attribute__((address_space(3))) void*)lds, 16, 0, 0);
}

// ---------------------------------------------------------------------------
// fp32 -> bf16 conversion: node_feats and the packed weight matrix Wcat.
// ---------------------------------------------------------------------------
__global__ __launch_bounds__(256) void convert_kernel(
    const float* __restrict__ node, const float* __restrict__ Wgx,
    const float* __restrict__ Wgk, const float* __restrict__ Wgq,
    __hip_bfloat16* __restrict__ node_bf, __hip_bfloat16* __restrict__ Wcat)
{
    const size_t NE = (size_t)Bb * Nn * INF_ / 4;
    const size_t WE = (size_t)OC * INF_ / 4;
    for (size_t i = (size_t)blockIdx.x * 256 + threadIdx.x; i < NE + WE;
         i += (size_t)gridDim.x * 256) {
        if (i < NE) {
            const float4 v = ((const float4*)node)[i];
            __hip_bfloat16* o = node_bf + i * 4;
            o[0] = __float2bfloat16(v.x); o[1] = __float2bfloat16(v.y);
            o[2] = __float2bfloat16(v.z); o[3] = __float2bfloat16(v.w);
        } else {
            const size_t j = i - NE;
            const size_t which = j / (1024 * INF_ / 4);
            const float* src = (which == 0) ? Wgx : (which == 1 ? Wgk : Wgq);
            const size_t srcj = j - which * (1024 * INF_ / 4);
            const float4 v = ((const float4*)src)[srcj];
            __hip_bfloat16* o = Wcat + j * 4;
            o[0] = __float2bfloat16(v.x); o[1] = __float2bfloat16(v.y);
            o[2] = __float2bfloat16(v.z); o[3] = __float2bfloat16(v.w);
        }
    }
}

// ---------------------------------------------------------------------------
// Fused node GEMM (bf16 MFMA), 256x256 tile, 8 waves (2m x 4n), BK=64 dbuf.
// LDS layout: rows of 64 shorts, granule g of row R stored at slot g^(R&7)
// (conflict-free ds_read_b128, measured 0 conflicts in R6). Staging via
// pre-swizzled per-lane global source; LDS dest linear (rule #21).
// Pipeline: STAGE(kt+1) issued first, overlaps 64 MFMA of kt; one
// vmcnt(0)+s_barrier per K-tile. Ordering proof: every wave lgkmcnt-drains
// its ds_reads of buf before MFMA, so by the end-of-iter barrier ALL reads
// of buf are complete -> next iter's STAGE into it is race-free.
// ---------------------------------------------------------------------------
__global__ __launch_bounds__(512, 2) void gemm_node_mfma(
    const __hip_bfloat16* __restrict__ A, const __hip_bfloat16* __restrict__ W,
    const float* __restrict__ bias_gx, __hip_bfloat16* __restrict__ Gcat)
{
    __shared__ short LDS[65536];          // A: [2][16384], B: 32768 + [2][16384]
    const int tid = threadIdx.x;
    const int lane = tid & 63;
    const int wid = tid >> 6;
    const int Wm = wid >> 2;              // 0..1 : 128-row half
    const int Wn = wid & 3;               // 0..3 : 64-col quarter

    // bijective XCD swizzle: nwg = 1572 = 8*196 + 4 (xcd 0-3 get 197)
    const int xcd = blockIdx.x & 7, sub = blockIdx.x >> 3;
    const int swz = (xcd < 4 ? xcd * 197 : 788 + (xcd - 4) * 196) + sub;
    const int mt = swz / 12, nt = swz % 12;
    const int m0 = mt * 256, o0 = nt * 256;

    const short* Asrc = (const short*)A;
    const short* Wsrc = (const short*)W;

    // staging map: thread tid covers LDS shorts [c*4096 + tid*8, +8) ->
    // row = c*64 + (tid>>3), slot = tid&7; source granule = slot ^ (row&7).
    const int srow = tid >> 3;
    const int gsrc = ((tid & 7) ^ ((tid >> 3) & 7)) * 8;   // shorts
    const int wchunk = (tid & ~63) * 8;                    // wave-uniform LDS base

    auto STAGE = [&](int buf, int kt) {
        const int k0 = kt * 64;
        short* Ad = &LDS[buf * 16384];
        short* Bd = &LDS[32768 + buf * 16384];
        #pragma unroll
        for (int c = 0; c < 4; ++c) {
            gload_lds16(Asrc + (size_t)(m0 + c * 64 + srow) * INF_ + k0 + gsrc,
                        Ad + c * 4096 + wchunk);
            gload_lds16(Wsrc + (size_t)(o0 + c * 64 + srow) * INF_ + k0 + gsrc,
                        Bd + c * 4096 + wchunk);
        }
    };

    // fragment read slots (row-bits cancel: (R&7) == (lane&7) for 16-aligned R)
    const int slot0 = ((lane >> 4) ^ (lane & 7)) * 8;          // ks=0
    const int slot1 = ((4 + (lane >> 4)) ^ (lane & 7)) * 8;    // ks=1
    const int rbase = lane & 15;

    f32x4 acc[8][4] = {};

    STAGE(0, 0);
    asm volatile("s_waitcnt vmcnt(0)" ::: "memory");
    __builtin_amdgcn_s_barrier();
    __builtin_amdgcn_sched_barrier(0);

    for (int kt = 0; kt < 8; ++kt) {
        const int buf = kt & 1;
        if (kt < 7) STAGE(buf ^ 1, kt + 1);
        const short* Ab = &LDS[buf * 16384];
        const short* Bb = &LDS[32768 + buf * 16384];

        bf16x8 bfr[4][2];
        #pragma unroll
        for (int ni = 0; ni < 4; ++ni) {
            const int R = Wn * 64 + ni * 16 + rbase;
            bfr[ni][0] = *(const bf16x8*)&Bb[R * 64 + slot0];
            bfr[ni][1] = *(const bf16x8*)&Bb[R * 64 + slot1];
        }
        #pragma unroll
        for (int half = 0; half < 2; ++half) {
            bf16x8 af[4][2];
            #pragma unroll
            for (int i = 0; i < 4; ++i) {
                const int R = Wm * 128 + (half * 4 + i) * 16 + rbase;
                af[i][0] = *(const bf16x8*)&Ab[R * 64 + slot0];
                af[i][1] = *(const bf16x8*)&Ab[R * 64 + slot1];
            }
            __builtin_amdgcn_s_setprio(1);
            #pragma unroll
            for (int i = 0; i < 4; ++i)
                #pragma unroll
                for (int ni = 0; ni < 4; ++ni) {
                    acc[half * 4 + i][ni] = __builtin_amdgcn_mfma_f32_16x16x32_bf16(
                        af[i][0], bfr[ni][0], acc[half * 4 + i][ni], 0, 0, 0);
                    acc[half * 4 + i][ni] = __builtin_amdgcn_mfma_f32_16x16x32_bf16(
                        af[i][1], bfr[ni][1], acc[half * 4 + i][ni], 0, 0, 0);
                }
            __builtin_amdgcn_s_setprio(0);
        }
        asm volatile("s_waitcnt vmcnt(0)" ::: "memory");
        __builtin_amdgcn_s_barrier();
        __builtin_amdgcn_sched_barrier(0);
    }

    // epilogue: bias + lrelu, direct bf16 stores
    #pragma unroll
    for (int ni = 0; ni < 4; ++ni) {
        const int o = o0 + Wn * 64 + ni * 16 + rbase;
        const float badd = (o < OUTF) ? bias_gx[o] : 0.f;
        #pragma unroll
        for (int mi = 0; mi < 8; ++mi) {
            #pragma unroll
            for (int r = 0; r < 4; ++r) {
                const int m = m0 + Wm * 128 + mi * 16 + (lane >> 4) * 4 + r;
                float v = acc[mi][ni][r] + badd;
                v = LRELU(v);
                Gcat[(size_t)m * OC + o] = __float2bfloat16(v);
            }
        }
    }
}

// ---------------------------------------------------------------------------
// Merged tabular GEMMs (fp32): which=0 -> T_X (bias b_tx), which=1 -> T_q.
// ---------------------------------------------------------------------------
__global__ __launch_bounds__(256) void gemm_tab(
    const float* __restrict__ Atab, const float* __restrict__ Wtx,
    const float* __restrict__ btx, const float* __restrict__ Wtq,
    float* __restrict__ Ctx, float* __restrict__ Ctq)
{
    const int which = blockIdx.x >> 4;
    const float* Wm = which ? Wtq : Wtx;
    float* C = which ? Ctq : Ctx;
    __shared__ float As[16][68];
    __shared__ float Ws[16][68];
    const int tid = threadIdx.x;
    const int tx = tid & 15;
    const int ty = tid >> 4;
    const int m0 = blockIdx.y * 64;
    const int o0 = (blockIdx.x & 15) * 64;

    float acc[4][4] = {};
    for (int k0 = 0; k0 < INF_; k0 += 16) {
        const int j = tid & 15;
        const int i = tid >> 4;
        #pragma unroll
        for (int r = 0; r < 4; ++r)
            As[j][i + 16 * r] = Atab[(size_t)(m0 + i + 16 * r) * INF_ + k0 + j];
        #pragma unroll
        for (int r = 0; r < 4; ++r)
            Ws[j][i + 16 * r] = Wm[(size_t)(o0 + i + 16 * r) * INF_ + k0 + j];
        __syncthreads();
        #pragma unroll
        for (int kk = 0; kk < 16; ++kk) {
            const float4 av = *(const float4*)&As[kk][ty * 4];
            const float4 wv = *(const float4*)&Ws[kk][tx * 4];
            const float a[4] = {av.x, av.y, av.z, av.w};
            const float w[4] = {wv.x, wv.y, wv.z, wv.w};
            #pragma unroll
            for (int r = 0; r < 4; ++r)
                #pragma unroll
                for (int c = 0; c < 4; ++c)
                    acc[r][c] += a[r] * w[c];
        }
        __syncthreads();
    }
    #pragma unroll
    for (int r = 0; r < 4; ++r) {
        const int m = m0 + ty * 4 + r;
        const int o = o0 + tx * 4;
        float4 v;
        float* vp = (float*)&v;
        #pragma unroll
        for (int c = 0; c < 4; ++c) {
            float t = acc[r][c] + (which ? 0.f : btx[o + c]);
            vp[c] = LRELU(t);
        }
        *(float4*)&C[(size_t)m * OUTF + o] = v;
    }
}

// ---------------------------------------------------------------------------
// Generic fp32 tiled GEMM (final Z GEMM only).
// ---------------------------------------------------------------------------
__global__ __launch_bounds__(256) void gemm_aw(
    const float* __restrict__ A, const float* __restrict__ W,
    const float* __restrict__ bias, float* __restrict__ C,
    int M, int K, int O)
{
    __shared__ float As[16][68];
    __shared__ float Ws[16][68];
    const int tid = threadIdx.x;
    const int tx = tid & 15;
    const int ty = tid >> 4;
    const int m0 = blockIdx.y * 64;
    const int o0 = blockIdx.x * 64;

    float acc[4][4] = {};
    for (int k0 = 0; k0 < K; k0 += 16) {
        const int j = tid & 15;
        const int i = tid >> 4;
        #pragma unroll
        for (int r = 0; r < 4; ++r)
            As[j][i + 16 * r] = A[(size_t)(m0 + i + 16 * r) * K + k0 + j];
        #pragma unroll
        for (int r = 0; r < 4; ++r)
            Ws[j][i + 16 * r] = W[(size_t)(o0 + i + 16 * r) * K + k0 + j];
        __syncthreads();
        #pragma unroll
        for (int kk = 0; kk < 16; ++kk) {
            const float4 av = *(const float4*)&As[kk][ty * 4];
            const float4 wv = *(const float4*)&Ws[kk][tx * 4];
            const float a[4] = {av.x, av.y, av.z, av.w};
            const float w[4] = {wv.x, wv.y, wv.z, wv.w};
            #pragma unroll
            for (int r = 0; r < 4; ++r)
                #pragma unroll
                for (int c = 0; c < 4; ++c)
                    acc[r][c] += a[r] * w[c];
        }
        __syncthreads();
    }
    #pragma unroll
    for (int r = 0; r < 4; ++r) {
        const int m = m0 + ty * 4 + r;
        const int o = o0 + tx * 4;
        float4 v;
        float* vp = (float*)&v;
        #pragma unroll
        for (int c = 0; c < 4; ++c) {
            float t = acc[r][c] + (bias ? bias[o + c] : 0.f);
            vp[c] = LRELU(t);
        }
        *(float4*)&C[(size_t)m * O + o] = v;
    }
}

// ---------------------------------------------------------------------------
// node_att softmax: s[b,n] = (1/32) * Tq[b,:] . Gk[b,n,:]; softmax over n; +1.
// ---------------------------------------------------------------------------
__global__ __launch_bounds__(256) void nodeatt_kernel(
    const float* __restrict__ Tq, const __hip_bfloat16* __restrict__ Gcat,
    float* __restrict__ att)
{
    const int b = blockIdx.x;
    __shared__ float tq[OUTF];
    __shared__ float sc[136];
    const int tid = threadIdx.x;
    for (int o = tid; o < OUTF; o += 256) tq[o] = Tq[(size_t)b * OUTF + o];
    __syncthreads();

    const int wave = tid >> 6, lane = tid & 63;
    for (int n = wave; n < Nn; n += 4) {
        const short4* gk = (const short4*)((const short*)Gcat + ((size_t)b * Nn + n) * OC + 1024);
        float s = 0.f;
        for (int o4 = lane; o4 < 256; o4 += 64) {
            const short4 v = gk[o4];
            s += tq[o4 * 4 + 0] * bf2f(v.x) + tq[o4 * 4 + 1] * bf2f(v.y)
               + tq[o4 * 4 + 2] * bf2f(v.z) + tq[o4 * 4 + 3] * bf2f(v.w);
        }
        #pragma unroll
        for (int off = 32; off; off >>= 1) s += __shfl_xor(s, off);
        if (lane == 0) sc[n] = s * (1.f / 32.f);
    }
    __syncthreads();

    if (tid < 64) {
        const float v1 = sc[tid];
        const float v2 = sc[tid + 64];
        const float v3 = (tid < 3) ? sc[tid + 128] : -1e30f;
        float m = fmaxf(fmaxf(v1, v2), v3);
        #pragma unroll
        for (int off = 32; off; off >>= 1) m = fmaxf(m, __shfl_xor(m, off));
        const float e1 = expf(v1 - m);
        const float e2 = expf(v2 - m);
        const float e3 = (tid < 3) ? expf(v3 - m) : 0.f;
        float s = e1 + e2 + e3;
        #pragma unroll
        for (int off = 32; off; off >>= 1) s += __shfl_xor(s, off);
        const float inv = 1.f / s;
        float* ab = att + (size_t)b * Nn;
        ab[tid] = e1 * inv + 1.f;
        ab[tid + 64] = e2 * inv + 1.f;
        if (tid < 3) ab[tid + 128] = e3 * inv + 1.f;
    }
}

// ---------------------------------------------------------------------------
// Transpose Graw head-slices: GrawT[bh][d][y] (y padded to 160 with zeros,
// stride YP). 64x64 LDS tiles, grid (4 d-tiles, 3 y-tiles, B*H).
// ---------------------------------------------------------------------------
__global__ __launch_bounds__(256) void transpose_kernel(
    const __hip_bfloat16* __restrict__ Gcat, __hip_bfloat16* __restrict__ GrawT)
{
    const int bh = blockIdx.z, b = bh >> 2, h = bh & 3;
    const int d0 = blockIdx.x * 64, y0 = blockIdx.y * 64;
    __shared__ short Ls[64 * 72];
    const int tid = threadIdx.x;
    const short* src = (const short*)Gcat + (size_t)b * Nn * OC + h * Dd + d0;
    short* dst = (short*)GrawT + (size_t)bh * 256 * YP + (size_t)d0 * YP;

    #pragma unroll
    for (int i = 0; i < 2; ++i) {
        const int task = i * 256 + tid;
        const int r = task >> 3, c8 = task & 7;
        const int y = y0 + r;
        bf16x8 v = {};
        if (y < Nn) v = *(const bf16x8*)(src + (size_t)y * OC + c8 * 8);
        *(bf16x8*)&Ls[r * 72 + c8 * 8] = v;
    }
    __syncthreads();
    #pragma unroll
    for (int i = 0; i < 2; ++i) {
        const int task = i * 256 + tid;
        const int dr = task >> 3, y8 = task & 7;
        const int yg = y0 + y8 * 8;
        if (yg < KAGG) {
            short tmp[8];
            #pragma unroll
            for (int j = 0; j < 8; ++j) tmp[j] = Ls[(y8 * 8 + j) * 72 + dr];
            *(bf16x8*)(dst + (size_t)dr * YP + yg) = *(bf16x8*)tmp;
        }
    }
}

// ---------------------------------------------------------------------------
// edge_mfma_rs (double-buffered, swizzled reads): 64x64 tile edge attention +
// sigmoid + edge write + slotted partial rowsums. Grid (3 yt, 3 xt, B*H).
// ---------------------------------------------------------------------------
__global__ __launch_bounds__(256) void edge_mfma_rs(
    const __hip_bfloat16* __restrict__ Gcat, const float* __restrict__ adj,
    float* __restrict__ edge, float* __restrict__ rs)
{
    const int bh = blockIdx.z;
    const int b = bh >> 2, h = bh & 3;
    const int x0 = blockIdx.y * 64, y0 = blockIdx.x * 64;
    __shared__ short Qs[2][64 * 32];
    __shared__ short Ks[2][64 * 32];
    const int tid = threadIdx.x;
    const int wave = tid >> 6, lane = tid & 63;
    const int wr = wave >> 1, wc = wave & 1;
    f32x4 acc[2][2] = {};
    const short* qbase = (const short*)Gcat + (size_t)b * Nn * OC + 2048 + h * Dd;
    const short* kbase = (const short*)Gcat + (size_t)b * Nn * OC + 1024 + h * Dd;
    const int lr = lane >> 2;
    const int g_src = ((lane & 3) ^ ((lane >> 3) & 3)) * 8;

    auto STAGE = [&](int buf, int k0) {
        const int c = wave;
        int xr = x0 + c * 16 + lr; if (xr > Nn - 1) xr = Nn - 1;
        gload_lds16(qbase + (size_t)xr * OC + k0 + g_src, &Qs[buf][c * 512]);
        int yr = y0 + c * 16 + lr; if (yr > Nn - 1) yr = Nn - 1;
        gload_lds16(kbase + (size_t)yr * OC + k0 + g_src, &Ks[buf][c * 512]);
    };

    STAGE(0, 0);
    for (int t = 0; t < 8; ++t) {
        const int buf = t & 1;
        if (t < 7) {
            STAGE(buf ^ 1, (t + 1) * 32);
            asm volatile("s_waitcnt vmcnt(2)" ::: "memory");
        } else {
            asm volatile("s_waitcnt vmcnt(0)" ::: "memory");
        }
        __builtin_amdgcn_s_barrier();
        __builtin_amdgcn_sched_barrier(0);
        const int sa = ((lane >> 4) ^ ((lane >> 1) & 3)) * 8;
        bf16x8 qf[2], kf[2];
        #pragma unroll
        for (int i = 0; i < 2; ++i) {
            qf[i] = *(const bf16x8*)&Qs[buf][(wr * 32 + i * 16 + (lane & 15)) * 32 + sa];
            kf[i] = *(const bf16x8*)&Ks[buf][(wc * 32 + i * 16 + (lane & 15)) * 32 + sa];
        }
        __builtin_amdgcn_s_setprio(1);
        #pragma unroll
        for (int mi = 0; mi < 2; ++mi)
            #pragma unroll
            for (int ni = 0; ni < 2; ++ni)
                acc[mi][ni] = __builtin_amdgcn_mfma_f32_16x16x32_bf16(
                    qf[mi], kf[ni], acc[mi][ni], 0, 0, 0);
        __builtin_amdgcn_s_setprio(0);
        __builtin_amdgcn_sched_barrier(0);
        if (t < 7) __builtin_amdgcn_s_barrier();
    }

    const int cc = lane & 15;
    const int rg = (lane >> 4) * 4;
    const float* adjb = adj + (size_t)b * Nn * Nn;
    float* edgeb = edge + (size_t)bh * Nn * Nn;
    float* rsb = rs + ((size_t)(blockIdx.x * 2 + wc) * (Bb * Hh) + bh) * Nn;
    #pragma unroll
    for (int mi = 0; mi < 2; ++mi) {
        float rsum[4] = {0.f, 0.f, 0.f, 0.f};
        #pragma unroll
        for (int ni = 0; ni < 2; ++ni) {
            const int y = y0 + wc * 32 + ni * 16 + cc;
            #pragma unroll
            for (int r = 0; r < 4; ++r) {
                const int x = x0 + wr * 32 + mi * 16 + rg + r;
                const float e = 1.f / (1.f + __expf(-acc[mi][ni][r] * (1.f / 16.f)));
                if (x < Nn && y < Nn) {
                    edgeb[x * Nn + y] = e;
                    rsum[r] += adjb[x * Nn + y] * e;
                }
            }
        }
        #pragma unroll
        for (int r = 0; r < 4; ++r) {
            float v = rsum[r];
            v += __shfl_xor(v, 1); v += __shfl_xor(v, 2);
            v += __shfl_xor(v, 4); v += __shfl_xor(v, 8);
            const int x = x0 + wr * 32 + mi * 16 + rg + r;
            if (cc == 0 && x < Nn) rsb[x] = v;
        }
    }
}

// ---------------------------------------------------------------------------
// wbuild (dinv merged): one block per bh. dinv from 6 rs slots in LDS, then
// Wb[bh][x][y] = dinvx*(adj*edge + I)*dinv_y*att_y, bf16, y-pad 160.
// ---------------------------------------------------------------------------
__global__ __launch_bounds__(256) void wbuild_kernel(
    const float* __restrict__ adj, const float* __restrict__ edge,
    const float* __restrict__ rs, const float* __restrict__ att,
    __hip_bfloat16* __restrict__ Wb)
{
    const int bh = blockIdx.x, b = bh >> 2;
    __shared__ float dxL[Nn], daL[Nn];
    const int tid = threadIdx.x;
    if (tid < Nn) {
        float s = 0.f;
        #pragma unroll
        for (int sl = 0; sl < 6; ++sl)
            s += rs[(size_t)sl * (Bb * Hh * Nn) + (size_t)bh * Nn + tid];
        const float dv = rsqrtf(s + 1.f);
        dxL[tid] = dv;
        daL[tid] = dv * att[(size_t)b * Nn + tid];
    }
    __syncthreads();
    const float* ab = adj + (size_t)b * Nn * Nn;
    const float* eb = edge + (size_t)bh * Nn * Nn;
    short* wbb = (short*)Wb + (size_t)bh * XP * YP;
    for (int task = tid; task < Nn * 20; task += 256) {
        const int x = task / 20, g = task % 20;
        const float dx = dxL[x];
        short outv[8];
        #pragma unroll
        for (int j = 0; j < 8; ++j) {
            const int y = g * 8 + j;
            float w = 0.f;
            if (y < Nn) {
                float a = ab[x * Nn + y] * eb[x * Nn + y];
                if (x == y) a += 1.f;
                w = dx * a * daL[y];
            }
            __hip_bfloat16 hb = __float2bfloat16(w);
            outv[j] = *(short*)&hb;
        }
        *(bf16x8*)(wbb + (size_t)x * YP + g * 8) = *(bf16x8*)outv;
    }
}

// ---------------------------------------------------------------------------
// Aggregation MFMA + fused graph-summary colsum:
// Gout[x][d] = sum_y Wb[x][y]*GrawT[d][y]; gnode[b][h*256+d] = sum_x wgs[x]*Gout.
// ---------------------------------------------------------------------------
__global__ __launch_bounds__(512) void agg_mfma(
    const __hip_bfloat16* __restrict__ Wb, const __hip_bfloat16* __restrict__ GrawT,
    const float* __restrict__ Wgs, float* __restrict__ Gout,
    float* __restrict__ gnode)
{
    const int bh = blockIdx.x, b = bh >> 2, h = bh & 3;
    __shared__ short As[XP * 40];
    __shared__ short Bs[256 * 40];
    __shared__ float wgsL[Nn];
    const int tid = threadIdx.x;
    const int wave = tid >> 6, lane = tid & 63;
    if (tid < Nn) wgsL[tid] = Wgs[tid];
    f32x4 acc[9][2] = {};
    const short* wsrc = (const short*)Wb + (size_t)bh * XP * YP;
    const short* gsrc = (const short*)GrawT + (size_t)bh * 256 * YP;

    for (int kc = 0; kc < 5; ++kc) {
        const int k0 = kc * 32;
        __syncthreads();
        #pragma unroll
        for (int i = 0; i < 2; ++i) {
            const int t = i * 512 + tid;
            if (t < 655) {
                const int row = t / 5, part = t - row * 5;
                gload_lds16(wsrc + (size_t)row * YP + k0 + part * 8,
                            &As[(i * 512 + (tid & ~63)) * 8]);
            }
        }
        #pragma unroll
        for (int i = 0; i < 3; ++i) {
            const int t = i * 512 + tid;
            if (t < 1280) {
                const int row = t / 5, part = t - row * 5;
                gload_lds16(gsrc + (size_t)row * YP + k0 + part * 8,
                            &Bs[(i * 512 + (tid & ~63)) * 8]);
            }
        }
        __syncthreads();
        bf16x8 af[9], bfr[2];
        #pragma unroll
        for (int mi = 0; mi < 9; ++mi)
            af[mi] = *(const bf16x8*)&As[(mi * 16 + (lane & 15)) * 40 + (lane >> 4) * 8];
        #pragma unroll
        for (int ni = 0; ni < 2; ++ni)
            bfr[ni] = *(const bf16x8*)&Bs[(wave * 32 + ni * 16 + (lane & 15)) * 40 + (lane >> 4) * 8];
        __builtin_amdgcn_s_setprio(1);
        #pragma unroll
        for (int mi = 0; mi < 9; ++mi)
            #pragma unroll
            for (int ni = 0; ni < 2; ++ni)
                acc[mi][ni] = __builtin_amdgcn_mfma_f32_16x16x32_bf16(
                    af[mi], bfr[ni], acc[mi][ni], 0, 0, 0);
        __builtin_amdgcn_s_setprio(0);
    }

    float* gob = Gout + (size_t)b * Nn * OUTF + h * Dd;
    float gp[2] = {0.f, 0.f};
    #pragma unroll
    for (int mi = 0; mi < 9; ++mi)
        #pragma unroll
        for (int ni = 0; ni < 2; ++ni) {
            const int d = wave * 32 + ni * 16 + (lane & 15);
            #pragma unroll
            for (int r = 0; r < 4; ++r) {
                const int x = mi * 16 + (lane >> 4) * 4 + r;
                if (x < Nn) {
                    gob[(size_t)x * OUTF + d] = acc[mi][ni][r];
                    gp[ni] += wgsL[x] * acc[mi][ni][r];
                }
            }
        }
    #pragma unroll
    for (int ni = 0; ni < 2; ++ni) {
        gp[ni] += __shfl_xor(gp[ni], 16);
        gp[ni] += __shfl_xor(gp[ni], 32);
        if (lane < 16)
            gnode[(size_t)b * OUTF + h * Dd + wave * 32 + ni * 16 + lane] = gp[ni];
    }
}

// ---------------------------------------------------------------------------
// Zin build: Zin[b][0:1024] = lrelu(gnode + bgs), Zin[b][1024:2048] = T_X.
// ---------------------------------------------------------------------------
__global__ __launch_bounds__(256) void zin_build(
    const float* __restrict__ gnode, const float* __restrict__ bgs,
    const float* __restrict__ Tx, float* __restrict__ Zin)
{
    const int idx = blockIdx.x * 256 + threadIdx.x;
    const int b = idx >> 10, o = idx & 1023;
    const float s = gnode[idx] + bgs[0];
    Zin[(size_t)b * 2048 + o] = LRELU(s);
    Zin[(size_t)b * 2048 + 1024 + o] = Tx[idx];
}

// ---------------------------------------------------------------------------
extern "C" void kernel_launch(void* const* d_in, const int* in_sizes, int n_in,
                              void* d_out, int out_size, void* d_ws, size_t ws_size,
                              hipStream_t stream) {
    const float* tab  = (const float*)d_in[0];
    const float* node = (const float*)d_in[1];
    const float* adj  = (const float*)d_in[2];
    const float* W_gx = (const float*)d_in[3];
    const float* b_gx = (const float*)d_in[4];
    const float* W_tx = (const float*)d_in[5];
    const float* b_tx = (const float*)d_in[6];
    const float* W_gk = (const float*)d_in[7];
    const float* W_tq = (const float*)d_in[8];
    const float* W_gq = (const float*)d_in[9];
    const float* W_gs = (const float*)d_in[10];
    const float* b_gs = (const float*)d_in[11];
    const float* W_zx = (const float*)d_in[12];
    const float* b_zx = (const float*)d_in[13];

    const size_t GX_ELEMS = (size_t)Bb * Nn * OUTF;   // 34,340,864
    const int M_NODE = Bb * Nn;                       // 33536

    float* out   = (float*)d_out;
    float* o_GX  = out;
    float* o_TX  = o_GX + GX_ELEMS;
    float* o_ZX  = o_TX + (size_t)Bb * OUTF;
    float* o_ATT = o_ZX + (size_t)Bb * OUTF;
    float* o_EDG = o_ATT + (size_t)Bb * Nn;

    // workspace: bf16 regions first, then fp32
    __hip_bfloat16* wb      = (__hip_bfloat16*)d_ws;
    __hip_bfloat16* w_nodeb = wb;                                          // 33536*512
    __hip_bfloat16* w_Wcat  = w_nodeb + (size_t)M_NODE * INF_;             // 3072*512
    __hip_bfloat16* w_Gcat  = w_Wcat + (size_t)OC * INF_;                  // 33536*3072
    __hip_bfloat16* w_GrawT = w_Gcat + (size_t)M_NODE * OC;                // 1024*256*168
    __hip_bfloat16* w_Wb    = w_GrawT + (size_t)Bb * Hh * 256 * YP;        // 1024*144*168
    float* wf       = (float*)(w_Wb + (size_t)Bb * Hh * XP * YP);
    float* w_Tq     = wf;
    float* w_Zin    = w_Tq + (size_t)Bb * OUTF;
    float* w_rs     = w_Zin + (size_t)Bb * 2 * OUTF;                       // 6*1024*131
    float* w_gnode  = w_rs + (size_t)6 * Bb * Hh * Nn;                     // 256*1024

    const dim3 blk(256);

    // 0. fp32 -> bf16
    convert_kernel<<<dim3(2048), blk, 0, stream>>>(node, W_gx, W_gk, W_gq,
                                                   w_nodeb, w_Wcat);
    // 1. merged tabular GEMMs (T_X + T_q)
    gemm_tab<<<dim3(32, 4), blk, 0, stream>>>(tab, W_tx, b_tx, W_tq, o_TX, w_Tq);
    // 2. fused node GEMM -> Gcat bf16 [33536][3072] (256x256 pipelined)
    gemm_node_mfma<<<dim3(131 * 12), dim3(512), 0, stream>>>(
        w_nodeb, w_Wcat, b_gx, w_Gcat);
    // 3. node attention -> o_ATT (softmax + 1)
    nodeatt_kernel<<<dim3(Bb), blk, 0, stream>>>(w_Tq, w_Gcat, o_ATT);
    // 4. transpose Graw head-slices -> GrawT
    transpose_kernel<<<dim3(4, 3, Bb * Hh), blk, 0, stream>>>(w_Gcat, w_GrawT);
    // 5. edge attention + slotted rowsums
    edge_mfma_rs<<<dim3(3, 3, Bb * Hh), blk, 0, stream>>>(w_Gcat, adj, o_EDG, w_rs);
    // 6. folded weight build (dinv merged) -> Wb
    wbuild_kernel<<<dim3(Bb * Hh), blk, 0, stream>>>(adj, o_EDG, w_rs, o_ATT, w_Wb);
    // 7. aggregation MFMA + fused gn colsum -> o_GX, gnode
    agg_mfma<<<dim3(Bb * Hh), dim3(512), 0, stream>>>(w_Wb, w_GrawT, W_gs,
                                                      o_GX, w_gnode);
    // 8. Zin build
    zin_build<<<dim3((Bb * OUTF) / 256), blk, 0, stream>>>(w_gnode, b_gs, o_TX, w_Zin);
    // 9. final Z GEMM
    gemm_aw<<<dim3(16, 4), blk, 0, stream>>>(w_Zin, W_zx, b_zx, o_ZX, Bb, 2 * OUTF, OUTF);
}